// Round 6
// baseline (1305.371 us; speedup 1.0000x reference)
//
#include <hip/hip_runtime.h>
#include <math.h>

#define NN 10000
#define NE 160000
#define FDIM 128
#define NRBF 20
#define PI_F 3.14159265358979323846f

// ---------------------------------------------------------------------------
// Pass 1: src histogram
// ---------------------------------------------------------------------------
__global__ void edge_count_kernel(const int* __restrict__ nbr, int* __restrict__ counts)
{
    int e = blockIdx.x * blockDim.x + threadIdx.x;
    if (e >= NE) return;
    atomicAdd(&counts[nbr[2 * e]], 1);
}

// ---------------------------------------------------------------------------
// Single-block exclusive scan over counts -> offsets (N+1)
// ---------------------------------------------------------------------------
__global__ void scan_kernel(const int* __restrict__ counts, int* __restrict__ offsets)
{
    __shared__ int sd[1024];
    __shared__ int carry;
    if (threadIdx.x == 0) carry = 0;
    __syncthreads();
    for (int base = 0; base < NN; base += 1024) {
        int i = base + threadIdx.x;
        int v = (i < NN) ? counts[i] : 0;
        sd[threadIdx.x] = v;
        __syncthreads();
        for (int off = 1; off < 1024; off <<= 1) {
            int t = (threadIdx.x >= off) ? sd[threadIdx.x - off] : 0;
            __syncthreads();
            sd[threadIdx.x] += t;
            __syncthreads();
        }
        if (i < NN) offsets[i] = carry + sd[threadIdx.x] - v;
        __syncthreads();
        if (threadIdx.x == 0) carry += sd[1023];
        __syncthreads();
    }
    if (threadIdx.x == 0) offsets[NN] = carry;
}

// ---------------------------------------------------------------------------
// Pass 2: compute geometry, write directly into CSR-permuted slots (fp32).
// ueP: float4 {ux,uy,uz,env} per edge.
// ---------------------------------------------------------------------------
__global__ void edge_geom_fill_kernel(const float* __restrict__ xyz, const int* __restrict__ nbr,
                                      const int* __restrict__ offsets, int* __restrict__ cnt2,
                                      int* __restrict__ dstP, float4* __restrict__ ueP,
                                      float* __restrict__ rbfP)
{
    int e = blockIdx.x * blockDim.x + threadIdx.x;
    if (e >= NE) return;
    int s = nbr[2 * e], d = nbr[2 * e + 1];
    float dx = xyz[3 * d + 0] - xyz[3 * s + 0];
    float dy = xyz[3 * d + 1] - xyz[3 * s + 1];
    float dz = xyz[3 * d + 2] - xyz[3 * s + 2];
    float dist = sqrtf(dx * dx + dy * dy + dz * dz);
    float inv = 1.0f / dist;
    int p = offsets[s] + atomicAdd(&cnt2[s], 1);
    dstP[p] = d;
    const float c = PI_F / 5.0f;
    float env = (dist < 5.0f) ? 0.5f * (cosf(c * dist) + 1.0f) : 0.0f;
    ueP[p] = make_float4(dx * inv, dy * inv, dz * inv, env);
#pragma unroll
    for (int k = 0; k < NRBF; k++)
        rbfP[NRBF * p + k] = sinf((float)(k + 1) * c * dist) * inv;
}

// ---------------------------------------------------------------------------
// fp32 GEMM v2: C[M,N] = act(A[M,K] @ W[K,N] + bias[N]); ACT=1 -> silu.
// BM=128, BN=64, BK=16, 256 threads, 8x4 micro-tile (32 FMA / 3 b128 reads).
// Requires K%16==0, N%64==0.
// ---------------------------------------------------------------------------
template <int ACT, int HB>
__global__ __launch_bounds__(256) void gemm2_kernel(const float* __restrict__ A,
                                                    const float* __restrict__ W,
                                                    const float* __restrict__ bias,
                                                    float* __restrict__ C,
                                                    int M, int K, int N)
{
    __shared__ __align__(16) float As[16][128];
    __shared__ __align__(16) float Ws[16][64];
    int tid = threadIdx.x;
    int tx = tid & 15, ty = tid >> 4;
    int row0 = blockIdx.y * 128, col0 = blockIdx.x * 64;
    float acc[8][4] = {};
    int la_r = tid >> 1;            // 0..127
    int la_c = (tid & 1) * 8;       // 0 or 8
    int lw_r = tid >> 4;            // 0..15
    int lw_c = (tid & 15) * 4;      // 0..60

    for (int k0 = 0; k0 < K; k0 += 16) {
        int ar = row0 + la_r;
        float4 av0 = make_float4(0.f, 0.f, 0.f, 0.f);
        float4 av1 = make_float4(0.f, 0.f, 0.f, 0.f);
        if (ar < M) {
            av0 = *(const float4*)&A[(size_t)ar * K + k0 + la_c];
            av1 = *(const float4*)&A[(size_t)ar * K + k0 + la_c + 4];
        }
        As[la_c + 0][la_r] = av0.x; As[la_c + 1][la_r] = av0.y;
        As[la_c + 2][la_r] = av0.z; As[la_c + 3][la_r] = av0.w;
        As[la_c + 4][la_r] = av1.x; As[la_c + 5][la_r] = av1.y;
        As[la_c + 6][la_r] = av1.z; As[la_c + 7][la_r] = av1.w;
        float4 wv = *(const float4*)&W[(size_t)(k0 + lw_r) * N + col0 + lw_c];
        *(float4*)&Ws[lw_r][lw_c] = wv;
        __syncthreads();
#pragma unroll
        for (int k = 0; k < 16; k++) {
            float a8[8], w4[4];
#pragma unroll
            for (int i = 0; i < 8; i++) a8[i] = As[k][ty * 8 + i];
#pragma unroll
            for (int j = 0; j < 4; j++) w4[j] = Ws[k][tx * 4 + j];
#pragma unroll
            for (int i = 0; i < 8; i++)
#pragma unroll
                for (int j = 0; j < 4; j++) acc[i][j] += a8[i] * w4[j];
        }
        __syncthreads();
    }
#pragma unroll
    for (int i = 0; i < 8; i++) {
        int r = row0 + ty * 8 + i;
        if (r >= M) continue;
        int c0 = col0 + tx * 4;
        float4 v;
        v.x = acc[i][0] + (HB ? bias[c0 + 0] : 0.f);
        v.y = acc[i][1] + (HB ? bias[c0 + 1] : 0.f);
        v.z = acc[i][2] + (HB ? bias[c0 + 2] : 0.f);
        v.w = acc[i][3] + (HB ? bias[c0 + 3] : 0.f);
        if (ACT) {
            v.x = v.x / (1.0f + expf(-v.x));
            v.y = v.y / (1.0f + expf(-v.y));
            v.z = v.z / (1.0f + expf(-v.z));
            v.w = v.w / (1.0f + expf(-v.w));
        }
        *(float4*)&C[(size_t)r * N + c0] = v;
    }
}

// ---------------------------------------------------------------------------
// Same as gemm2 but A = concat(A0, A1) along columns; K fixed = 256 (128+128).
// ---------------------------------------------------------------------------
template <int ACT>
__global__ __launch_bounds__(256) void gemm2_cat_kernel(const float* __restrict__ A0,
                                                        const float* __restrict__ A1,
                                                        const float* __restrict__ W,
                                                        const float* __restrict__ bias,
                                                        float* __restrict__ C,
                                                        int M, int N)
{
    __shared__ __align__(16) float As[16][128];
    __shared__ __align__(16) float Ws[16][64];
    int tid = threadIdx.x;
    int tx = tid & 15, ty = tid >> 4;
    int row0 = blockIdx.y * 128, col0 = blockIdx.x * 64;
    float acc[8][4] = {};
    int la_r = tid >> 1;
    int la_c = (tid & 1) * 8;
    int lw_r = tid >> 4;
    int lw_c = (tid & 15) * 4;

    for (int k0 = 0; k0 < 256; k0 += 16) {
        int ar = row0 + la_r;
        float4 av0 = make_float4(0.f, 0.f, 0.f, 0.f);
        float4 av1 = make_float4(0.f, 0.f, 0.f, 0.f);
        if (ar < M) {
            int col = k0 + la_c;
            const float* s0 = (col < 128) ? &A0[(size_t)ar * 128 + col]
                                          : &A1[(size_t)ar * 128 + (col - 128)];
            av0 = *(const float4*)s0;
            int col2 = col + 4;
            const float* s1 = (col2 < 128) ? &A0[(size_t)ar * 128 + col2]
                                           : &A1[(size_t)ar * 128 + (col2 - 128)];
            av1 = *(const float4*)s1;
        }
        As[la_c + 0][la_r] = av0.x; As[la_c + 1][la_r] = av0.y;
        As[la_c + 2][la_r] = av0.z; As[la_c + 3][la_r] = av0.w;
        As[la_c + 4][la_r] = av1.x; As[la_c + 5][la_r] = av1.y;
        As[la_c + 6][la_r] = av1.z; As[la_c + 7][la_r] = av1.w;
        float4 wv = *(const float4*)&W[(size_t)(k0 + lw_r) * N + col0 + lw_c];
        *(float4*)&Ws[lw_r][lw_c] = wv;
        __syncthreads();
#pragma unroll
        for (int k = 0; k < 16; k++) {
            float a8[8], w4[4];
#pragma unroll
            for (int i = 0; i < 8; i++) a8[i] = As[k][ty * 8 + i];
#pragma unroll
            for (int j = 0; j < 4; j++) w4[j] = Ws[k][tx * 4 + j];
#pragma unroll
            for (int i = 0; i < 8; i++)
#pragma unroll
                for (int j = 0; j < 4; j++) acc[i][j] += a8[i] * w4[j];
        }
        __syncthreads();
    }
#pragma unroll
    for (int i = 0; i < 8; i++) {
        int r = row0 + ty * 8 + i;
        if (r >= M) continue;
        int c0 = col0 + tx * 4;
        float4 v;
        v.x = acc[i][0] + bias[c0 + 0];
        v.y = acc[i][1] + bias[c0 + 1];
        v.z = acc[i][2] + bias[c0 + 2];
        v.w = acc[i][3] + bias[c0 + 3];
        if (ACT) {
            v.x = v.x / (1.0f + expf(-v.x));
            v.y = v.y / (1.0f + expf(-v.y));
            v.z = v.z / (1.0f + expf(-v.z));
            v.w = v.w / (1.0f + expf(-v.w));
        }
        *(float4*)&C[(size_t)r * N + c0] = v;
    }
}

// ---------------------------------------------------------------------------
// Gather message kernel (unchanged from R5): 2 nodes/block, dist_W pinned in
// registers via opaque asm; V/Vbar planar n*384 + c*128 + f.
// ---------------------------------------------------------------------------
__global__ __launch_bounds__(256, 2) void gather_kernel(
    const int* __restrict__ offsets, const int* __restrict__ dstP,
    const float4* __restrict__ ueP, const float* __restrict__ rbfP,
    const float* __restrict__ phi,
    const float* __restrict__ distW, const float* __restrict__ distb,
    const float* __restrict__ Vold, const float* __restrict__ Vbold,
    float* __restrict__ H, float* __restrict__ Sbar,
    float* __restrict__ Vnew, float* __restrict__ Vbnew)
{
    int n = (blockIdx.x << 1) | (threadIdx.x >> 7);
    int f = threadIdx.x & 127;

    float wv[100];
#pragma unroll
    for (int k = 0; k < NRBF; k++)
#pragma unroll
        for (int c = 0; c < 5; c++)
            wv[k * 5 + c] = distW[k * 640 + c * 128 + f];
#pragma unroll
    for (int i = 0; i < 100; i++) asm volatile("" : "+v"(wv[i]));

    float b0 = distb[f], b1 = distb[128 + f], b2 = distb[256 + f],
          b3 = distb[384 + f], b4 = distb[512 + f];

    float accH = 0.f, accS = 0.f;
    float accV0 = 0.f, accV1 = 0.f, accV2 = 0.f;
    float accB0 = 0.f, accB1 = 0.f, accB2 = 0.f;
    int e0 = offsets[n], e1 = offsets[n + 1];
    for (int p = e0; p < e1; ++p) {
        int d = dstP[p];
        float4 ue = ueP[p];
        float r[NRBF];
#pragma unroll
        for (int q = 0; q < NRBF / 4; q++) {
            float4 rv = *(const float4*)&rbfP[NRBF * p + 4 * q];
            r[4 * q + 0] = rv.x; r[4 * q + 1] = rv.y;
            r[4 * q + 2] = rv.z; r[4 * q + 3] = rv.w;
        }
        float w0 = b0, w1 = b1, w2 = b2, w3 = b3, w4 = b4;
#pragma unroll
        for (int k = 0; k < NRBF; k++) {
            float rk = r[k];
            w0 += rk * wv[k * 5 + 0];
            w1 += rk * wv[k * 5 + 1];
            w2 += rk * wv[k * 5 + 2];
            w3 += rk * wv[k * 5 + 3];
            w4 += rk * wv[k * 5 + 4];
        }
        float ev = ue.w;
        const float* ph = phi + (size_t)d * 640;
        float i0 = ph[f] * w0 * ev;
        float i1 = ph[128 + f] * w1 * ev;
        float i2 = ph[256 + f] * w2 * ev;
        float i3 = ph[384 + f] * w3 * ev;
        float i4 = ph[512 + f] * w4 * ev;
        accH += i1;
        accS += i3;
        const float* vd  = Vold  + (size_t)d * 384;
        const float* vbd = Vbold + (size_t)d * 384;
        accV0 += i2 * ue.x + i0 * vd[f];
        accV1 += i2 * ue.y + i0 * vd[128 + f];
        accV2 += i2 * ue.z + i0 * vd[256 + f];
        accB0 += i2 * ue.x + i4 * vbd[f];
        accB1 += i2 * ue.y + i4 * vbd[128 + f];
        accB2 += i2 * ue.z + i4 * vbd[256 + f];
    }
    H[n * 128 + f] += accH;
    Sbar[n * 128 + f] += accS;
    const float* vo  = Vold  + (size_t)n * 384;
    const float* vbo = Vbold + (size_t)n * 384;
    float* vn  = Vnew  + (size_t)n * 384;
    float* vbn = Vbnew + (size_t)n * 384;
    vn[f]       = vo[f]       + accV0;
    vn[128 + f] = vo[128 + f] + accV1;
    vn[256 + f] = vo[256 + f] + accV2;
    vbn[f]       = vbo[f]       + accB0;
    vbn[128 + f] = vbo[128 + f] + accB1;
    vbn[256 + f] = vbo[256 + f] + accB2;
}

// ---------------------------------------------------------------------------
// Per-(n,g) norm/dot from planar u_v, v_v.
// ---------------------------------------------------------------------------
__global__ void norm_kernel(const float* __restrict__ u_v, const float* __restrict__ v_v,
                            float* __restrict__ vnorm, float* __restrict__ dotb)
{
    int idx = blockIdx.x * blockDim.x + threadIdx.x;
    if (idx >= NN * 128) return;
    int n = idx >> 7, g = idx & 127;
    const float* up = u_v + (size_t)n * 384;
    const float* vp = v_v + (size_t)n * 384;
    float u0 = up[g], u1 = up[128 + g], u2 = up[256 + g];
    float v0 = vp[g], v1 = vp[128 + g], v2 = vp[256 + g];
    dotb[idx] = u0 * v0 + u1 * v1 + u2 * v2;
    vnorm[idx] = sqrtf(v0 * v0 + v1 * v1 + v2 * v2 + 1e-15f);
}

// ---------------------------------------------------------------------------
// Final per-layer update: H += a1*dot + a2 ; V += a0*u_v.
// LAST=0: V stays planar in-place. LAST=1: write interleaved (n,f,3) to Vout.
// ---------------------------------------------------------------------------
template <int LAST>
__global__ void final_update_kernel(const float* __restrict__ a,
                                    const float* __restrict__ dotb,
                                    const float* __restrict__ u_v,
                                    float* __restrict__ H,
                                    float* __restrict__ Vplanar,
                                    float* __restrict__ Vout)
{
    int idx = blockIdx.x * blockDim.x + threadIdx.x;
    if (idx >= NN * 128) return;
    int n = idx >> 7, g = idx & 127;
    float a0 = a[n * 384 + g];
    float a1 = a[n * 384 + 128 + g];
    float a2 = a[n * 384 + 256 + g];
    H[idx] += a1 * dotb[idx] + a2;
    float* vp = Vplanar + (size_t)n * 384;
    const float* up = u_v + (size_t)n * 384;
    float v0 = vp[g]       + a0 * up[g];
    float v1 = vp[128 + g] + a0 * up[128 + g];
    float v2 = vp[256 + g] + a0 * up[256 + g];
    if (LAST) {
        float* o = Vout + (size_t)n * 384 + g * 3;
        o[0] = v0; o[1] = v1; o[2] = v2;
    } else {
        vp[g] = v0; vp[128 + g] = v1; vp[256 + g] = v2;
    }
}

// ---------------------------------------------------------------------------
extern "C" void kernel_launch(void* const* d_in, const int* in_sizes, int n_in,
                              void* d_out, int out_size, void* d_ws, size_t ws_size,
                              hipStream_t stream)
{
    const float* xyz    = (const float*)d_in[0];
    const int*   nbr    = (const int*)d_in[1];
    const float* H_in   = (const float*)d_in[3];
    const float* msgW1  = (const float*)d_in[4];
    const float* msgb1  = (const float*)d_in[5];
    const float* msgW2  = (const float*)d_in[6];
    const float* msgb2  = (const float*)d_in[7];
    const float* distW  = (const float*)d_in[8];
    const float* distb  = (const float*)d_in[9];
    const float* updU   = (const float*)d_in[10];
    const float* updV   = (const float*)d_in[11];
    const float* updW1  = (const float*)d_in[12];
    const float* updb1  = (const float*)d_in[13];
    const float* updW2  = (const float*)d_in[14];
    const float* updb2  = (const float*)d_in[15];

    float* out  = (float*)d_out;
    float* H    = out;                 // N*128
    float* Vout = out + NN * 128;      // N*384 interleaved (n,f,3)

    // ---- workspace carve (floats) ----
    float* f = (float*)d_ws;
    float* Va   = f; f += NN * 384;    // planar V buffers
    float* Vb   = f; f += NN * 384;
    float* Vba  = f; f += NN * 384;
    float* Vbb  = f; f += NN * 384;
    float* Sbar = f; f += NN * 128;
    float* X1   = f; f += NN * 384;    // W1/uW1 hidden, reused as v_v
    float* phi  = f; f += NN * 640;
    float* u_v  = f; f += NN * 384;
    float4* ueP = (float4*)f; f += NE * 4;
    float* rbfP  = f; f += NE * NRBF;
    int* ip = (int*)f;
    int* counts  = ip; ip += NN;
    int* offsets = ip; ip += NN + 1;
    int* cnt2    = ip; ip += NN;
    int* dstP    = ip; ip += NE;
    float* v_v = X1;                   // alias: live only between uv-GEMMs and norm
    // aliases into dead phi region (phi dead after gather each layer)
    float* vnorm = phi;
    float* dotb  = phi + NN * 128;
    float* abuf  = phi + NN * 256;     // N*384

    // ---- init ----
    hipMemsetAsync(counts, 0, NN * sizeof(int), stream);
    hipMemsetAsync(cnt2, 0, NN * sizeof(int), stream);
    hipMemsetAsync(Va, 0, (size_t)NN * 384 * sizeof(float), stream);
    hipMemsetAsync(Vba, 0, (size_t)NN * 384 * sizeof(float), stream);
    hipMemsetAsync(Sbar, 0, (size_t)NN * 128 * sizeof(float), stream);
    hipMemcpyAsync(H, H_in, (size_t)NN * 128 * sizeof(float),
                   hipMemcpyDeviceToDevice, stream);

    // ---- edge CSR + geometry (2-pass, writes permuted directly) ----
    edge_count_kernel<<<(NE + 255) / 256, 256, 0, stream>>>(nbr, counts);
    scan_kernel<<<1, 1024, 0, stream>>>(counts, offsets);
    edge_geom_fill_kernel<<<(NE + 255) / 256, 256, 0, stream>>>(xyz, nbr, offsets, cnt2,
                                                                dstP, ueP, rbfP);

    for (int l = 0; l < 3; ++l) {
        const float* W1 = msgW1 + (size_t)l * 256 * 256;
        const float* b1 = msgb1 + (size_t)l * 256;
        const float* W2 = msgW2 + (size_t)l * 256 * 640;
        const float* b2 = msgb2 + (size_t)l * 640;
        const float* dW = distW + (size_t)l * NRBF * 640;
        const float* db = distb + (size_t)l * 640;
        const float* Ul = updU + (size_t)l * 128 * 128;
        const float* Vl = updV + (size_t)l * 128 * 128;
        const float* uW1 = updW1 + (size_t)l * 256 * 128;
        const float* ub1 = updb1 + (size_t)l * 128;
        const float* uW2 = updW2 + (size_t)l * 128 * 384;
        const float* ub2 = updb2 + (size_t)l * 384;

        float *Vold, *Vnew, *Vbold, *Vbnew;
        if (l == 0)      { Vold = Va; Vnew = Vb; Vbold = Vba; Vbnew = Vbb; }
        else if (l == 1) { Vold = Vb; Vnew = Va; Vbold = Vbb; Vbnew = Vba; }
        else             { Vold = Va; Vnew = Vb; Vbold = Vba; Vbnew = Vbb; }

        // phi = silu([H|Sbar] @ W1 + b1) @ W2 + b2
        {
            dim3 g(256 / 64, (NN + 127) / 128);
            gemm2_cat_kernel<1><<<g, 256, 0, stream>>>(H, Sbar, W1, b1, X1, NN, 256);
        }
        {
            dim3 g(640 / 64, (NN + 127) / 128);
            gemm2_kernel<0, 1><<<g, 256, 0, stream>>>(X1, W2, b2, phi, NN, 256, 640);
        }

        // message gather (2 nodes per 256-thread block)
        gather_kernel<<<NN / 2, 256, 0, stream>>>(offsets, dstP, ueP, rbfP,
                                                  phi, dW, db, Vold, Vbold,
                                                  H, Sbar, Vnew, Vbnew);

        // u_v = Vplanar @ U ; v_v = Vplanar @ Vm  (planar view = [3N x 128] GEMM)
        {
            dim3 g(128 / 64, (3 * NN + 127) / 128);
            gemm2_kernel<0, 0><<<g, 256, 0, stream>>>(Vnew, Ul, nullptr, u_v, 3 * NN, 128, 128);
            gemm2_kernel<0, 0><<<g, 256, 0, stream>>>(Vnew, Vl, nullptr, v_v, 3 * NN, 128, 128);
        }
        norm_kernel<<<(NN * 128 + 255) / 256, 256, 0, stream>>>(u_v, v_v, vnorm, dotb);

        // a = silu([H|v_norm] @ uW1 + ub1) @ uW2 + ub2
        {
            dim3 g(128 / 64, (NN + 127) / 128);
            gemm2_cat_kernel<1><<<g, 256, 0, stream>>>(H, vnorm, uW1, ub1, X1, NN, 128);
        }
        {
            dim3 g(384 / 64, (NN + 127) / 128);
            gemm2_kernel<0, 1><<<g, 256, 0, stream>>>(X1, uW2, ub2, abuf, NN, 128, 384);
        }

        // H += a1*dot + a2 ; V += a0*u_v
        if (l < 2)
            final_update_kernel<0><<<(NN * 128 + 255) / 256, 256, 0, stream>>>(
                abuf, dotb, u_v, H, Vnew, nullptr);
        else
            final_update_kernel<1><<<(NN * 128 + 255) / 256, 256, 0, stream>>>(
                abuf, dotb, u_v, H, Vnew, Vout);
    }
}

// Round 7
// 1030.038 us; speedup vs baseline: 1.2673x; 1.2673x over previous
//
#include <hip/hip_runtime.h>
#include <math.h>

#define NN 10000
#define NE 160000
#define FDIM 128
#define NRBF 20
#define PI_F 3.14159265358979323846f
#define LDP 40  // LDS row pitch in bf16 elems (80 B -> 16B-aligned b128 rows)

typedef short bf16x8 __attribute__((ext_vector_type(8)));
typedef float f32x4 __attribute__((ext_vector_type(4)));

__device__ __forceinline__ unsigned short f2bf_rne(float v) {
    unsigned int u = __float_as_uint(v);
    u += 0x7FFF + ((u >> 16) & 1);
    return (unsigned short)(u >> 16);
}
__device__ __forceinline__ float bf2f(unsigned short b) {
    return __uint_as_float(((unsigned int)b) << 16);
}

// ---------------------------------------------------------------------------
// Pass 1: src histogram
// ---------------------------------------------------------------------------
__global__ void edge_count_kernel(const int* __restrict__ nbr, int* __restrict__ counts)
{
    int e = blockIdx.x * blockDim.x + threadIdx.x;
    if (e >= NE) return;
    atomicAdd(&counts[nbr[2 * e]], 1);
}

// ---------------------------------------------------------------------------
// Single-block exclusive scan over counts -> offsets (N+1)
// ---------------------------------------------------------------------------
__global__ void scan_kernel(const int* __restrict__ counts, int* __restrict__ offsets)
{
    __shared__ int sd[1024];
    __shared__ int carry;
    if (threadIdx.x == 0) carry = 0;
    __syncthreads();
    for (int base = 0; base < NN; base += 1024) {
        int i = base + threadIdx.x;
        int v = (i < NN) ? counts[i] : 0;
        sd[threadIdx.x] = v;
        __syncthreads();
        for (int off = 1; off < 1024; off <<= 1) {
            int t = (threadIdx.x >= off) ? sd[threadIdx.x - off] : 0;
            __syncthreads();
            sd[threadIdx.x] += t;
            __syncthreads();
        }
        if (i < NN) offsets[i] = carry + sd[threadIdx.x] - v;
        __syncthreads();
        if (threadIdx.x == 0) carry += sd[1023];
        __syncthreads();
    }
    if (threadIdx.x == 0) offsets[NN] = carry;
}

// ---------------------------------------------------------------------------
// Pass 2: compute geometry, write directly into CSR-permuted slots (fp32).
// ---------------------------------------------------------------------------
__global__ void edge_geom_fill_kernel(const float* __restrict__ xyz, const int* __restrict__ nbr,
                                      const int* __restrict__ offsets, int* __restrict__ cnt2,
                                      int* __restrict__ dstP, float4* __restrict__ ueP,
                                      float* __restrict__ rbfP)
{
    int e = blockIdx.x * blockDim.x + threadIdx.x;
    if (e >= NE) return;
    int s = nbr[2 * e], d = nbr[2 * e + 1];
    float dx = xyz[3 * d + 0] - xyz[3 * s + 0];
    float dy = xyz[3 * d + 1] - xyz[3 * s + 1];
    float dz = xyz[3 * d + 2] - xyz[3 * s + 2];
    float dist = sqrtf(dx * dx + dy * dy + dz * dz);
    float inv = 1.0f / dist;
    int p = offsets[s] + atomicAdd(&cnt2[s], 1);
    dstP[p] = d;
    const float c = PI_F / 5.0f;
    float env = (dist < 5.0f) ? 0.5f * (cosf(c * dist) + 1.0f) : 0.0f;
    ueP[p] = make_float4(dx * inv, dy * inv, dz * inv, env);
#pragma unroll
    for (int k = 0; k < NRBF; k++)
        rbfP[NRBF * p + k] = sinf((float)(k + 1) * c * dist) * inv;
}

// ---------------------------------------------------------------------------
// Split-bf16 MFMA GEMM: C[M,N] = act(A[M,K] @ W[K,N] + bias); fp32 in/out.
// x = hi + lo (bf16 each); D = Ah*Bh + Ah*Bl + Al*Bh  (err ~2^-16 rel).
// Block 256 thr = 4 waves; tile 64x64; BK=32 (one 16x16x32 MFMA K-step).
// Wave w: rows (w&1)*32, cols (w>>1)*32 -> 2x2 16x16 C-tiles.
// CAT=1: A = concat(A0,A1) cols (each 128 wide), K must be 256.
// ---------------------------------------------------------------------------
template <int ACT, int CAT>
__global__ __launch_bounds__(256) void gemm3_kernel(
    const float* __restrict__ A0, const float* __restrict__ A1,
    const float* __restrict__ W, const float* __restrict__ bias,
    float* __restrict__ C, int M, int K, int N)
{
    __shared__ __align__(16) unsigned short Ah[64 * LDP];
    __shared__ __align__(16) unsigned short Al[64 * LDP];
    __shared__ __align__(16) unsigned short Bh[64 * LDP];
    __shared__ __align__(16) unsigned short Bl[64 * LDP];

    int tid = threadIdx.x;
    int row0 = blockIdx.y * 64, col0 = blockIdx.x * 64;
    int lane = tid & 63, wave = tid >> 6;
    int mb = (wave & 1) * 32, nb = (wave >> 1) * 32;
    int lm = lane & 15, quad = lane >> 4;

    f32x4 acc[2][2] = {};

    int ra = tid >> 2, kq = tid & 3;   // A stage: row ra(0..63), k-quads kq*4, kq*4+16
    int kr = tid >> 3, nq = tid & 7;   // B stage: k-row kr(0..31), n-quads nq*4, nq*4+32

    for (int k0 = 0; k0 < K; k0 += 32) {
        // ---- stage A (64 rows x 32 k) ----
        {
            int ar = row0 + ra;
            float4 a0 = make_float4(0.f, 0.f, 0.f, 0.f);
            float4 a1 = make_float4(0.f, 0.f, 0.f, 0.f);
            if (ar < M) {
                const float* Ab;
                if (CAT) Ab = (k0 < 128) ? A0 + (size_t)ar * 128 + k0
                                         : A1 + (size_t)ar * 128 + (k0 - 128);
                else     Ab = A0 + (size_t)ar * K + k0;
                a0 = *(const float4*)(Ab + kq * 4);
                a1 = *(const float4*)(Ab + kq * 4 + 16);
            }
            float v0[4] = {a0.x, a0.y, a0.z, a0.w};
            float v1[4] = {a1.x, a1.y, a1.z, a1.w};
            ushort4 h0, l0, h1, l1;
            unsigned short* hp0 = (unsigned short*)&h0;
            unsigned short* lp0 = (unsigned short*)&l0;
            unsigned short* hp1 = (unsigned short*)&h1;
            unsigned short* lp1 = (unsigned short*)&l1;
#pragma unroll
            for (int i = 0; i < 4; i++) {
                unsigned short h = f2bf_rne(v0[i]);
                hp0[i] = h; lp0[i] = f2bf_rne(v0[i] - bf2f(h));
                unsigned short g = f2bf_rne(v1[i]);
                hp1[i] = g; lp1[i] = f2bf_rne(v1[i] - bf2f(g));
            }
            *(ushort4*)&Ah[ra * LDP + kq * 4]      = h0;
            *(ushort4*)&Al[ra * LDP + kq * 4]      = l0;
            *(ushort4*)&Ah[ra * LDP + kq * 4 + 16] = h1;
            *(ushort4*)&Al[ra * LDP + kq * 4 + 16] = l1;
        }
        // ---- stage B (32 k x 64 n), transposed into [n][k] ----
        {
            const float* Wb = &W[(size_t)(k0 + kr) * N + col0];
            float4 b0 = *(const float4*)(Wb + nq * 4);
            float4 b1 = *(const float4*)(Wb + nq * 4 + 32);
            float v0[4] = {b0.x, b0.y, b0.z, b0.w};
            float v1[4] = {b1.x, b1.y, b1.z, b1.w};
#pragma unroll
            for (int i = 0; i < 4; i++) {
                int n = nq * 4 + i;
                unsigned short h = f2bf_rne(v0[i]);
                Bh[n * LDP + kr] = h;
                Bl[n * LDP + kr] = f2bf_rne(v0[i] - bf2f(h));
                int n2 = n + 32;
                unsigned short g = f2bf_rne(v1[i]);
                Bh[n2 * LDP + kr] = g;
                Bl[n2 * LDP + kr] = f2bf_rne(v1[i] - bf2f(g));
            }
        }
        __syncthreads();
        // ---- compute: frags + 12 MFMAs ----
        bf16x8 fah[2], fal[2], fbh[2], fbl[2];
#pragma unroll
        for (int mt = 0; mt < 2; mt++) {
            int r = mb + mt * 16 + lm;
            fah[mt] = *(const bf16x8*)&Ah[r * LDP + quad * 8];
            fal[mt] = *(const bf16x8*)&Al[r * LDP + quad * 8];
        }
#pragma unroll
        for (int nt = 0; nt < 2; nt++) {
            int n = nb + nt * 16 + lm;
            fbh[nt] = *(const bf16x8*)&Bh[n * LDP + quad * 8];
            fbl[nt] = *(const bf16x8*)&Bl[n * LDP + quad * 8];
        }
#pragma unroll
        for (int mt = 0; mt < 2; mt++)
#pragma unroll
            for (int nt = 0; nt < 2; nt++) {
                acc[mt][nt] = __builtin_amdgcn_mfma_f32_16x16x32_bf16(
                    fah[mt], fbh[nt], acc[mt][nt], 0, 0, 0);
                acc[mt][nt] = __builtin_amdgcn_mfma_f32_16x16x32_bf16(
                    fah[mt], fbl[nt], acc[mt][nt], 0, 0, 0);
                acc[mt][nt] = __builtin_amdgcn_mfma_f32_16x16x32_bf16(
                    fal[mt], fbh[nt], acc[mt][nt], 0, 0, 0);
            }
        __syncthreads();
    }
    // ---- epilogue: C/D layout col=lane&15, row=quad*4+reg ----
#pragma unroll
    for (int mt = 0; mt < 2; mt++)
#pragma unroll
        for (int nt = 0; nt < 2; nt++) {
            int c = col0 + nb + nt * 16 + lm;
            float bv = bias ? bias[c] : 0.f;
#pragma unroll
            for (int reg = 0; reg < 4; reg++) {
                int r = row0 + mb + mt * 16 + quad * 4 + reg;
                if (r >= M) continue;
                float v = acc[mt][nt][reg] + bv;
                if (ACT) v = v / (1.0f + expf(-v));
                C[(size_t)r * N + c] = v;
            }
        }
}

// ---------------------------------------------------------------------------
// Gather message kernel (R5, protected): 2 nodes/block, dist_W pinned via
// opaque asm; V/Vbar planar n*384 + c*128 + f.
// ---------------------------------------------------------------------------
__global__ __launch_bounds__(256, 2) void gather_kernel(
    const int* __restrict__ offsets, const int* __restrict__ dstP,
    const float4* __restrict__ ueP, const float* __restrict__ rbfP,
    const float* __restrict__ phi,
    const float* __restrict__ distW, const float* __restrict__ distb,
    const float* __restrict__ Vold, const float* __restrict__ Vbold,
    float* __restrict__ H, float* __restrict__ Sbar,
    float* __restrict__ Vnew, float* __restrict__ Vbnew)
{
    int n = (blockIdx.x << 1) | (threadIdx.x >> 7);
    int f = threadIdx.x & 127;

    float wv[100];
#pragma unroll
    for (int k = 0; k < NRBF; k++)
#pragma unroll
        for (int c = 0; c < 5; c++)
            wv[k * 5 + c] = distW[k * 640 + c * 128 + f];
#pragma unroll
    for (int i = 0; i < 100; i++) asm volatile("" : "+v"(wv[i]));

    float b0 = distb[f], b1 = distb[128 + f], b2 = distb[256 + f],
          b3 = distb[384 + f], b4 = distb[512 + f];

    float accH = 0.f, accS = 0.f;
    float accV0 = 0.f, accV1 = 0.f, accV2 = 0.f;
    float accB0 = 0.f, accB1 = 0.f, accB2 = 0.f;
    int e0 = offsets[n], e1 = offsets[n + 1];
    for (int p = e0; p < e1; ++p) {
        int d = dstP[p];
        float4 ue = ueP[p];
        float r[NRBF];
#pragma unroll
        for (int q = 0; q < NRBF / 4; q++) {
            float4 rv = *(const float4*)&rbfP[NRBF * p + 4 * q];
            r[4 * q + 0] = rv.x; r[4 * q + 1] = rv.y;
            r[4 * q + 2] = rv.z; r[4 * q + 3] = rv.w;
        }
        float w0 = b0, w1 = b1, w2 = b2, w3 = b3, w4 = b4;
#pragma unroll
        for (int k = 0; k < NRBF; k++) {
            float rk = r[k];
            w0 += rk * wv[k * 5 + 0];
            w1 += rk * wv[k * 5 + 1];
            w2 += rk * wv[k * 5 + 2];
            w3 += rk * wv[k * 5 + 3];
            w4 += rk * wv[k * 5 + 4];
        }
        float ev = ue.w;
        const float* ph = phi + (size_t)d * 640;
        float i0 = ph[f] * w0 * ev;
        float i1 = ph[128 + f] * w1 * ev;
        float i2 = ph[256 + f] * w2 * ev;
        float i3 = ph[384 + f] * w3 * ev;
        float i4 = ph[512 + f] * w4 * ev;
        accH += i1;
        accS += i3;
        const float* vd  = Vold  + (size_t)d * 384;
        const float* vbd = Vbold + (size_t)d * 384;
        accV0 += i2 * ue.x + i0 * vd[f];
        accV1 += i2 * ue.y + i0 * vd[128 + f];
        accV2 += i2 * ue.z + i0 * vd[256 + f];
        accB0 += i2 * ue.x + i4 * vbd[f];
        accB1 += i2 * ue.y + i4 * vbd[128 + f];
        accB2 += i2 * ue.z + i4 * vbd[256 + f];
    }
    H[n * 128 + f] += accH;
    Sbar[n * 128 + f] += accS;
    const float* vo  = Vold  + (size_t)n * 384;
    const float* vbo = Vbold + (size_t)n * 384;
    float* vn  = Vnew  + (size_t)n * 384;
    float* vbn = Vbnew + (size_t)n * 384;
    vn[f]       = vo[f]       + accV0;
    vn[128 + f] = vo[128 + f] + accV1;
    vn[256 + f] = vo[256 + f] + accV2;
    vbn[f]       = vbo[f]       + accB0;
    vbn[128 + f] = vbo[128 + f] + accB1;
    vbn[256 + f] = vbo[256 + f] + accB2;
}

// ---------------------------------------------------------------------------
// u_v/v_v einsum + v_norm + dot (R5). 4 nodes/block, planar V and u_v.
// ---------------------------------------------------------------------------
__global__ __launch_bounds__(128) void uv_kernel(const float* __restrict__ V,
                                                 const float* __restrict__ U,
                                                 const float* __restrict__ Vm,
                                                 float* __restrict__ u_v,
                                                 float* __restrict__ vnorm,
                                                 float* __restrict__ dotb)
{
    int g = threadIdx.x;
    int n0 = blockIdx.x * 4;
    __shared__ float sV[4 * 384];
    for (int i = g; i < 4 * 384; i += 128) {
        int nn = i / 384, rem = i % 384;
        int node = n0 + nn;
        sV[i] = (node < NN) ? V[(size_t)node * 384 + rem] : 0.f;
    }
    __syncthreads();
    float ua[4][3] = {}, va[4][3] = {};
    for (int ff = 0; ff < 128; ++ff) {
        float uf = U[ff * 128 + g];
        float vf = Vm[ff * 128 + g];
#pragma unroll
        for (int nn = 0; nn < 4; nn++) {
            float v0 = sV[nn * 384 + ff];
            float v1 = sV[nn * 384 + 128 + ff];
            float v2 = sV[nn * 384 + 256 + ff];
            ua[nn][0] += v0 * uf; ua[nn][1] += v1 * uf; ua[nn][2] += v2 * uf;
            va[nn][0] += v0 * vf; va[nn][1] += v1 * vf; va[nn][2] += v2 * vf;
        }
    }
#pragma unroll
    for (int nn = 0; nn < 4; nn++) {
        int node = n0 + nn;
        if (node >= NN) continue;
        float d = ua[nn][0] * va[nn][0] + ua[nn][1] * va[nn][1] + ua[nn][2] * va[nn][2];
        float vn = sqrtf(va[nn][0] * va[nn][0] + va[nn][1] * va[nn][1] +
                         va[nn][2] * va[nn][2] + 1e-15f);
        u_v[(size_t)node * 384 + g]       = ua[nn][0];
        u_v[(size_t)node * 384 + 128 + g] = ua[nn][1];
        u_v[(size_t)node * 384 + 256 + g] = ua[nn][2];
        vnorm[node * 128 + g] = vn;
        dotb[node * 128 + g] = d;
    }
}

// ---------------------------------------------------------------------------
// Final per-layer update: H += a1*dot + a2 ; V += a0*u_v.
// ---------------------------------------------------------------------------
template <int LAST>
__global__ void final_update_kernel(const float* __restrict__ a,
                                    const float* __restrict__ dotb,
                                    const float* __restrict__ u_v,
                                    float* __restrict__ H,
                                    float* __restrict__ Vplanar,
                                    float* __restrict__ Vout)
{
    int idx = blockIdx.x * blockDim.x + threadIdx.x;
    if (idx >= NN * 128) return;
    int n = idx >> 7, g = idx & 127;
    float a0 = a[n * 384 + g];
    float a1 = a[n * 384 + 128 + g];
    float a2 = a[n * 384 + 256 + g];
    H[idx] += a1 * dotb[idx] + a2;
    float* vp = Vplanar + (size_t)n * 384;
    const float* up = u_v + (size_t)n * 384;
    float v0 = vp[g]       + a0 * up[g];
    float v1 = vp[128 + g] + a0 * up[128 + g];
    float v2 = vp[256 + g] + a0 * up[256 + g];
    if (LAST) {
        float* o = Vout + (size_t)n * 384 + g * 3;
        o[0] = v0; o[1] = v1; o[2] = v2;
    } else {
        vp[g] = v0; vp[128 + g] = v1; vp[256 + g] = v2;
    }
}

// ---------------------------------------------------------------------------
extern "C" void kernel_launch(void* const* d_in, const int* in_sizes, int n_in,
                              void* d_out, int out_size, void* d_ws, size_t ws_size,
                              hipStream_t stream)
{
    const float* xyz    = (const float*)d_in[0];
    const int*   nbr    = (const int*)d_in[1];
    const float* H_in   = (const float*)d_in[3];
    const float* msgW1  = (const float*)d_in[4];
    const float* msgb1  = (const float*)d_in[5];
    const float* msgW2  = (const float*)d_in[6];
    const float* msgb2  = (const float*)d_in[7];
    const float* distW  = (const float*)d_in[8];
    const float* distb  = (const float*)d_in[9];
    const float* updU   = (const float*)d_in[10];
    const float* updV   = (const float*)d_in[11];
    const float* updW1  = (const float*)d_in[12];
    const float* updb1  = (const float*)d_in[13];
    const float* updW2  = (const float*)d_in[14];
    const float* updb2  = (const float*)d_in[15];

    float* out  = (float*)d_out;
    float* H    = out;                 // N*128
    float* Vout = out + NN * 128;      // N*384 interleaved (n,f,3)

    // ---- workspace carve (floats) ----
    float* f = (float*)d_ws;
    float* Va   = f; f += NN * 384;    // planar V buffers
    float* Vb   = f; f += NN * 384;
    float* Vba  = f; f += NN * 384;
    float* Vbb  = f; f += NN * 384;
    float* Sbar = f; f += NN * 128;
    float* X1   = f; f += NN * 256;
    float* phi  = f; f += NN * 640;
    float* u_v  = f; f += NN * 384;
    float4* ueP = (float4*)f; f += NE * 4;
    float* rbfP  = f; f += NE * NRBF;
    int* ip = (int*)f;
    int* counts  = ip; ip += NN;
    int* offsets = ip; ip += NN + 1;
    int* cnt2    = ip; ip += NN;
    int* dstP    = ip; ip += NE;
    // aliases into dead phi region (phi dead after gather each layer)
    float* vnorm = phi;
    float* dotb  = phi + NN * 128;
    float* abuf  = phi + NN * 256;     // N*384

    // ---- init ----
    hipMemsetAsync(counts, 0, NN * sizeof(int), stream);
    hipMemsetAsync(cnt2, 0, NN * sizeof(int), stream);
    hipMemsetAsync(Va, 0, (size_t)NN * 384 * sizeof(float), stream);
    hipMemsetAsync(Vba, 0, (size_t)NN * 384 * sizeof(float), stream);
    hipMemsetAsync(Sbar, 0, (size_t)NN * 128 * sizeof(float), stream);
    hipMemcpyAsync(H, H_in, (size_t)NN * 128 * sizeof(float),
                   hipMemcpyDeviceToDevice, stream);

    // ---- edge CSR + geometry (2-pass, writes permuted directly) ----
    edge_count_kernel<<<(NE + 255) / 256, 256, 0, stream>>>(nbr, counts);
    scan_kernel<<<1, 1024, 0, stream>>>(counts, offsets);
    edge_geom_fill_kernel<<<(NE + 255) / 256, 256, 0, stream>>>(xyz, nbr, offsets, cnt2,
                                                                dstP, ueP, rbfP);

    for (int l = 0; l < 3; ++l) {
        const float* W1 = msgW1 + (size_t)l * 256 * 256;
        const float* b1 = msgb1 + (size_t)l * 256;
        const float* W2 = msgW2 + (size_t)l * 256 * 640;
        const float* b2 = msgb2 + (size_t)l * 640;
        const float* dW = distW + (size_t)l * NRBF * 640;
        const float* db = distb + (size_t)l * 640;
        const float* Ul = updU + (size_t)l * 128 * 128;
        const float* Vl = updV + (size_t)l * 128 * 128;
        const float* uW1 = updW1 + (size_t)l * 256 * 128;
        const float* ub1 = updb1 + (size_t)l * 128;
        const float* uW2 = updW2 + (size_t)l * 128 * 384;
        const float* ub2 = updb2 + (size_t)l * 384;

        float *Vold, *Vnew, *Vbold, *Vbnew;
        if (l == 0)      { Vold = Va; Vnew = Vb; Vbold = Vba; Vbnew = Vbb; }
        else if (l == 1) { Vold = Vb; Vnew = Va; Vbold = Vbb; Vbnew = Vba; }
        else             { Vold = Va; Vnew = Vb; Vbold = Vba; Vbnew = Vbb; }

        // phi = silu([H|Sbar] @ W1 + b1) @ W2 + b2
        {
            dim3 g(256 / 64, (NN + 63) / 64);
            gemm3_kernel<1, 1><<<g, 256, 0, stream>>>(H, Sbar, W1, b1, X1, NN, 256, 256);
        }
        {
            dim3 g(640 / 64, (NN + 63) / 64);
            gemm3_kernel<0, 0><<<g, 256, 0, stream>>>(X1, nullptr, W2, b2, phi, NN, 256, 640);
        }

        // message gather (2 nodes per 256-thread block)
        gather_kernel<<<NN / 2, 256, 0, stream>>>(offsets, dstP, ueP, rbfP,
                                                  phi, dW, db, Vold, Vbold,
                                                  H, Sbar, Vnew, Vbnew);

        // u_v, v_v, v_norm, dot
        uv_kernel<<<(NN + 3) / 4, 128, 0, stream>>>(Vnew, Ul, Vl, u_v, vnorm, dotb);

        // a = silu([H|v_norm] @ uW1 + ub1) @ uW2 + ub2
        {
            dim3 g(128 / 64, (NN + 63) / 64);
            gemm3_kernel<1, 1><<<g, 256, 0, stream>>>(H, vnorm, uW1, ub1, X1, NN, 256, 128);
        }
        {
            dim3 g(384 / 64, (NN + 63) / 64);
            gemm3_kernel<0, 0><<<g, 256, 0, stream>>>(X1, nullptr, uW2, ub2, abuf, NN, 128, 384);
        }

        // H += a1*dot + a2 ; V += a0*u_v
        if (l < 2)
            final_update_kernel<0><<<(NN * 128 + 255) / 256, 256, 0, stream>>>(
                abuf, dotb, u_v, H, Vnew, nullptr);
        else
            final_update_kernel<1><<<(NN * 128 + 255) / 256, 256, 0, stream>>>(
                abuf, dotb, u_v, H, Vnew, Vout);
    }
}

// Round 8
// 932.257 us; speedup vs baseline: 1.4002x; 1.1049x over previous
//
#include <hip/hip_runtime.h>
#include <math.h>

#define NN 10000
#define NE 160000
#define FDIM 128
#define NRBF 20
#define PI_F 3.14159265358979323846f
#define LDP 40  // LDS row pitch in bf16 elems (80 B -> 16B-aligned b128 rows)

typedef short bf16x8 __attribute__((ext_vector_type(8)));
typedef float f32x4 __attribute__((ext_vector_type(4)));

__device__ __forceinline__ unsigned short f2bf_rne(float v) {
    unsigned int u = __float_as_uint(v);
    u += 0x7FFF + ((u >> 16) & 1);
    return (unsigned short)(u >> 16);
}
__device__ __forceinline__ float bf2f(unsigned short b) {
    return __uint_as_float(((unsigned int)b) << 16);
}

// ---------------------------------------------------------------------------
// Pass 1: src histogram
// ---------------------------------------------------------------------------
__global__ void edge_count_kernel(const int* __restrict__ nbr, int* __restrict__ counts)
{
    int e = blockIdx.x * blockDim.x + threadIdx.x;
    if (e >= NE) return;
    atomicAdd(&counts[nbr[2 * e]], 1);
}

// ---------------------------------------------------------------------------
// Single-block exclusive scan over counts -> offsets (N+1)
// ---------------------------------------------------------------------------
__global__ void scan_kernel(const int* __restrict__ counts, int* __restrict__ offsets)
{
    __shared__ int sd[1024];
    __shared__ int carry;
    if (threadIdx.x == 0) carry = 0;
    __syncthreads();
    for (int base = 0; base < NN; base += 1024) {
        int i = base + threadIdx.x;
        int v = (i < NN) ? counts[i] : 0;
        sd[threadIdx.x] = v;
        __syncthreads();
        for (int off = 1; off < 1024; off <<= 1) {
            int t = (threadIdx.x >= off) ? sd[threadIdx.x - off] : 0;
            __syncthreads();
            sd[threadIdx.x] += t;
            __syncthreads();
        }
        if (i < NN) offsets[i] = carry + sd[threadIdx.x] - v;
        __syncthreads();
        if (threadIdx.x == 0) carry += sd[1023];
        __syncthreads();
    }
    if (threadIdx.x == 0) offsets[NN] = carry;
}

// ---------------------------------------------------------------------------
// Pass 2: compute geometry, write directly into CSR-permuted slots (fp32).
// ---------------------------------------------------------------------------
__global__ void edge_geom_fill_kernel(const float* __restrict__ xyz, const int* __restrict__ nbr,
                                      const int* __restrict__ offsets, int* __restrict__ cnt2,
                                      int* __restrict__ dstP, float4* __restrict__ ueP,
                                      float* __restrict__ rbfP)
{
    int e = blockIdx.x * blockDim.x + threadIdx.x;
    if (e >= NE) return;
    int s = nbr[2 * e], d = nbr[2 * e + 1];
    float dx = xyz[3 * d + 0] - xyz[3 * s + 0];
    float dy = xyz[3 * d + 1] - xyz[3 * s + 1];
    float dz = xyz[3 * d + 2] - xyz[3 * s + 2];
    float dist = sqrtf(dx * dx + dy * dy + dz * dz);
    float inv = 1.0f / dist;
    int p = offsets[s] + atomicAdd(&cnt2[s], 1);
    dstP[p] = d;
    const float c = PI_F / 5.0f;
    float env = (dist < 5.0f) ? 0.5f * (cosf(c * dist) + 1.0f) : 0.0f;
    ueP[p] = make_float4(dx * inv, dy * inv, dz * inv, env);
#pragma unroll
    for (int k = 0; k < NRBF; k++)
        rbfP[NRBF * p + k] = sinf((float)(k + 1) * c * dist) * inv;
}

// ---------------------------------------------------------------------------
// Build [U|V] concatenated weights for the uv GEMM, all 3 layers.
// ---------------------------------------------------------------------------
__global__ void build_uvcat_kernel(const float* __restrict__ updU,
                                   const float* __restrict__ updV,
                                   float* __restrict__ UVcat)
{
    int idx = blockIdx.x * blockDim.x + threadIdx.x;
    if (idx >= 3 * 128 * 256) return;
    int l = idx / (128 * 256);
    int rem = idx % (128 * 256);
    int k = rem >> 8, j = rem & 255;
    UVcat[idx] = (j < 128) ? updU[(l * 128 + k) * 128 + j]
                           : updV[(l * 128 + k) * 128 + (j - 128)];
}

// ---------------------------------------------------------------------------
// Split-bf16 MFMA GEMM (R7, protected): C = act(A@W + bias); fp32 in/out.
// ---------------------------------------------------------------------------
template <int ACT, int CAT>
__global__ __launch_bounds__(256) void gemm3_kernel(
    const float* __restrict__ A0, const float* __restrict__ A1,
    const float* __restrict__ W, const float* __restrict__ bias,
    float* __restrict__ C, int M, int K, int N)
{
    __shared__ __align__(16) unsigned short Ah[64 * LDP];
    __shared__ __align__(16) unsigned short Al[64 * LDP];
    __shared__ __align__(16) unsigned short Bh[64 * LDP];
    __shared__ __align__(16) unsigned short Bl[64 * LDP];

    int tid = threadIdx.x;
    int row0 = blockIdx.y * 64, col0 = blockIdx.x * 64;
    int lane = tid & 63, wave = tid >> 6;
    int mb = (wave & 1) * 32, nb = (wave >> 1) * 32;
    int lm = lane & 15, quad = lane >> 4;

    f32x4 acc[2][2] = {};

    int ra = tid >> 2, kq = tid & 3;
    int kr = tid >> 3, nq = tid & 7;

    for (int k0 = 0; k0 < K; k0 += 32) {
        {
            int ar = row0 + ra;
            float4 a0 = make_float4(0.f, 0.f, 0.f, 0.f);
            float4 a1 = make_float4(0.f, 0.f, 0.f, 0.f);
            if (ar < M) {
                const float* Ab;
                if (CAT) Ab = (k0 < 128) ? A0 + (size_t)ar * 128 + k0
                                         : A1 + (size_t)ar * 128 + (k0 - 128);
                else     Ab = A0 + (size_t)ar * K + k0;
                a0 = *(const float4*)(Ab + kq * 4);
                a1 = *(const float4*)(Ab + kq * 4 + 16);
            }
            float v0[4] = {a0.x, a0.y, a0.z, a0.w};
            float v1[4] = {a1.x, a1.y, a1.z, a1.w};
            ushort4 h0, l0, h1, l1;
            unsigned short* hp0 = (unsigned short*)&h0;
            unsigned short* lp0 = (unsigned short*)&l0;
            unsigned short* hp1 = (unsigned short*)&h1;
            unsigned short* lp1 = (unsigned short*)&l1;
#pragma unroll
            for (int i = 0; i < 4; i++) {
                unsigned short h = f2bf_rne(v0[i]);
                hp0[i] = h; lp0[i] = f2bf_rne(v0[i] - bf2f(h));
                unsigned short g = f2bf_rne(v1[i]);
                hp1[i] = g; lp1[i] = f2bf_rne(v1[i] - bf2f(g));
            }
            *(ushort4*)&Ah[ra * LDP + kq * 4]      = h0;
            *(ushort4*)&Al[ra * LDP + kq * 4]      = l0;
            *(ushort4*)&Ah[ra * LDP + kq * 4 + 16] = h1;
            *(ushort4*)&Al[ra * LDP + kq * 4 + 16] = l1;
        }
        {
            const float* Wb = &W[(size_t)(k0 + kr) * N + col0];
            float4 b0 = *(const float4*)(Wb + nq * 4);
            float4 b1 = *(const float4*)(Wb + nq * 4 + 32);
            float v0[4] = {b0.x, b0.y, b0.z, b0.w};
            float v1[4] = {b1.x, b1.y, b1.z, b1.w};
#pragma unroll
            for (int i = 0; i < 4; i++) {
                int n = nq * 4 + i;
                unsigned short h = f2bf_rne(v0[i]);
                Bh[n * LDP + kr] = h;
                Bl[n * LDP + kr] = f2bf_rne(v0[i] - bf2f(h));
                int n2 = n + 32;
                unsigned short g = f2bf_rne(v1[i]);
                Bh[n2 * LDP + kr] = g;
                Bl[n2 * LDP + kr] = f2bf_rne(v1[i] - bf2f(g));
            }
        }
        __syncthreads();
        bf16x8 fah[2], fal[2], fbh[2], fbl[2];
#pragma unroll
        for (int mt = 0; mt < 2; mt++) {
            int r = mb + mt * 16 + lm;
            fah[mt] = *(const bf16x8*)&Ah[r * LDP + quad * 8];
            fal[mt] = *(const bf16x8*)&Al[r * LDP + quad * 8];
        }
#pragma unroll
        for (int nt = 0; nt < 2; nt++) {
            int n = nb + nt * 16 + lm;
            fbh[nt] = *(const bf16x8*)&Bh[n * LDP + quad * 8];
            fbl[nt] = *(const bf16x8*)&Bl[n * LDP + quad * 8];
        }
#pragma unroll
        for (int mt = 0; mt < 2; mt++)
#pragma unroll
            for (int nt = 0; nt < 2; nt++) {
                acc[mt][nt] = __builtin_amdgcn_mfma_f32_16x16x32_bf16(
                    fah[mt], fbh[nt], acc[mt][nt], 0, 0, 0);
                acc[mt][nt] = __builtin_amdgcn_mfma_f32_16x16x32_bf16(
                    fah[mt], fbl[nt], acc[mt][nt], 0, 0, 0);
                acc[mt][nt] = __builtin_amdgcn_mfma_f32_16x16x32_bf16(
                    fal[mt], fbh[nt], acc[mt][nt], 0, 0, 0);
            }
        __syncthreads();
    }
#pragma unroll
    for (int mt = 0; mt < 2; mt++)
#pragma unroll
        for (int nt = 0; nt < 2; nt++) {
            int c = col0 + nb + nt * 16 + lm;
            float bv = bias ? bias[c] : 0.f;
#pragma unroll
            for (int reg = 0; reg < 4; reg++) {
                int r = row0 + mb + mt * 16 + quad * 4 + reg;
                if (r >= M) continue;
                float v = acc[mt][nt][reg] + bv;
                if (ACT) v = v / (1.0f + expf(-v));
                C[(size_t)r * N + c] = v;
            }
        }
}

// ---------------------------------------------------------------------------
// Gather, plane-split: 1 node per 256-thread block. Waves 0-1 (half=0)
// compute planes {gate_v, ds, dir} -> H, Vnew (reads Vold); waves 2-3
// (half=1) compute planes {dir, dsbar, gate_vbar} -> Sbar, Vbnew (reads
// Vbold). Each thread pins only 60 distW values -> ~2x occupancy vs R7.
// phi plane offsets are po, po+128, po+256 with po = half*256.
// ---------------------------------------------------------------------------
__global__ __launch_bounds__(256, 4) void gather_kernel(
    const int* __restrict__ offsets, const int* __restrict__ dstP,
    const float4* __restrict__ ueP, const float* __restrict__ rbfP,
    const float* __restrict__ phi,
    const float* __restrict__ distW, const float* __restrict__ distb,
    const float* __restrict__ Vold, const float* __restrict__ Vbold,
    float* __restrict__ H, float* __restrict__ Sbar,
    float* __restrict__ Vnew, float* __restrict__ Vbnew)
{
    int n = blockIdx.x;
    int t = threadIdx.x;
    int half = t >> 7;          // wave-uniform (waves 0-1 vs 2-3)
    int f = t & 127;
    int po = half * 256;

    float wv[60];
#pragma unroll
    for (int k = 0; k < NRBF; k++)
#pragma unroll
        for (int c = 0; c < 3; c++)
            wv[k * 3 + c] = distW[k * 640 + po + c * 128 + f];
#pragma unroll
    for (int i = 0; i < 60; i++) asm volatile("" : "+v"(wv[i]));

    float bA = distb[po + f], bB = distb[po + 128 + f], bC = distb[po + 256 + f];

    const float* Vsel = half ? Vbold : Vold;

    float sacc = 0.f, acc0 = 0.f, acc1 = 0.f, acc2 = 0.f;
    int e0 = offsets[n], e1 = offsets[n + 1];
    for (int p = e0; p < e1; ++p) {
        int d = dstP[p];
        float4 ue = ueP[p];
        float r[NRBF];
#pragma unroll
        for (int q = 0; q < NRBF / 4; q++) {
            float4 rv = *(const float4*)&rbfP[NRBF * p + 4 * q];
            r[4 * q + 0] = rv.x; r[4 * q + 1] = rv.y;
            r[4 * q + 2] = rv.z; r[4 * q + 3] = rv.w;
        }
        float wA = bA, wB = bB, wC = bC;
#pragma unroll
        for (int k = 0; k < NRBF; k++) {
            float rk = r[k];
            wA += rk * wv[k * 3 + 0];
            wB += rk * wv[k * 3 + 1];
            wC += rk * wv[k * 3 + 2];
        }
        float ev = ue.w;
        const float* ph = phi + (size_t)d * 640 + po;
        float iA = ph[f] * wA * ev;
        float iB = ph[128 + f] * wB * ev;
        float iC = ph[256 + f] * wC * ev;
        // half0: iA=gate_v, iB=ds,    iC=dir
        // half1: iA=dir,    iB=dsbar, iC=gate_vbar
        float dir  = half ? iA : iC;
        float gate = half ? iC : iA;
        sacc += iB;
        const float* vd = Vsel + (size_t)d * 384;
        acc0 += dir * ue.x + gate * vd[f];
        acc1 += dir * ue.y + gate * vd[128 + f];
        acc2 += dir * ue.z + gate * vd[256 + f];
    }
    if (half == 0) H[n * 128 + f] += sacc;
    else           Sbar[n * 128 + f] += sacc;
    const float* vo = Vsel + (size_t)n * 384;
    float* vn = (half ? Vbnew : Vnew) + (size_t)n * 384;
    vn[f]       = vo[f]       + acc0;
    vn[128 + f] = vo[128 + f] + acc1;
    vn[256 + f] = vo[256 + f] + acc2;
}

// ---------------------------------------------------------------------------
// norm/dot from the fused uv2 buffer [3N x 256]: row r=n*3+c, u at col g,
// v at col 128+g.
// ---------------------------------------------------------------------------
__global__ void norm_kernel(const float* __restrict__ uv2,
                            float* __restrict__ vnorm, float* __restrict__ dotb)
{
    int idx = blockIdx.x * blockDim.x + threadIdx.x;
    if (idx >= NN * 128) return;
    int n = idx >> 7, g = idx & 127;
    const float* base = uv2 + (size_t)n * 768;
    float u0 = base[g],       u1 = base[256 + g], u2 = base[512 + g];
    float v0 = base[128 + g], v1 = base[384 + g], v2 = base[640 + g];
    dotb[idx] = u0 * v0 + u1 * v1 + u2 * v2;
    vnorm[idx] = sqrtf(v0 * v0 + v1 * v1 + v2 * v2 + 1e-15f);
}

// ---------------------------------------------------------------------------
// Final per-layer update: H += a1*dot + a2 ; V += a0*u_v (u from uv2).
// ---------------------------------------------------------------------------
template <int LAST>
__global__ void final_update_kernel(const float* __restrict__ a,
                                    const float* __restrict__ dotb,
                                    const float* __restrict__ uv2,
                                    float* __restrict__ H,
                                    float* __restrict__ Vplanar,
                                    float* __restrict__ Vout)
{
    int idx = blockIdx.x * blockDim.x + threadIdx.x;
    if (idx >= NN * 128) return;
    int n = idx >> 7, g = idx & 127;
    float a0 = a[n * 384 + g];
    float a1 = a[n * 384 + 128 + g];
    float a2 = a[n * 384 + 256 + g];
    H[idx] += a1 * dotb[idx] + a2;
    float* vp = Vplanar + (size_t)n * 384;
    const float* ub = uv2 + (size_t)n * 768;
    float v0 = vp[g]       + a0 * ub[g];
    float v1 = vp[128 + g] + a0 * ub[256 + g];
    float v2 = vp[256 + g] + a0 * ub[512 + g];
    if (LAST) {
        float* o = Vout + (size_t)n * 384 + g * 3;
        o[0] = v0; o[1] = v1; o[2] = v2;
    } else {
        vp[g] = v0; vp[128 + g] = v1; vp[256 + g] = v2;
    }
}

// ---------------------------------------------------------------------------
extern "C" void kernel_launch(void* const* d_in, const int* in_sizes, int n_in,
                              void* d_out, int out_size, void* d_ws, size_t ws_size,
                              hipStream_t stream)
{
    const float* xyz    = (const float*)d_in[0];
    const int*   nbr    = (const int*)d_in[1];
    const float* H_in   = (const float*)d_in[3];
    const float* msgW1  = (const float*)d_in[4];
    const float* msgb1  = (const float*)d_in[5];
    const float* msgW2  = (const float*)d_in[6];
    const float* msgb2  = (const float*)d_in[7];
    const float* distW  = (const float*)d_in[8];
    const float* distb  = (const float*)d_in[9];
    const float* updU   = (const float*)d_in[10];
    const float* updV   = (const float*)d_in[11];
    const float* updW1  = (const float*)d_in[12];
    const float* updb1  = (const float*)d_in[13];
    const float* updW2  = (const float*)d_in[14];
    const float* updb2  = (const float*)d_in[15];

    float* out  = (float*)d_out;
    float* H    = out;                 // N*128
    float* Vout = out + NN * 128;      // N*384 interleaved (n,f,3)

    // ---- workspace carve (floats) ----
    float* f = (float*)d_ws;
    float* Va   = f; f += NN * 384;    // planar V buffers
    float* Vb   = f; f += NN * 384;
    float* Vba  = f; f += NN * 384;
    float* Vbb  = f; f += NN * 384;
    float* Sbar = f; f += NN * 128;
    float* X1   = f; f += NN * 256;
    float* phi  = f; f += NN * 640;
    float* uv2  = f; f += NN * 768;    // [3N x 256] fused u_v|v_v
    float* UVcat = f; f += 3 * 128 * 256;
    float4* ueP = (float4*)f; f += NE * 4;
    float* rbfP  = f; f += NE * NRBF;
    int* ip = (int*)f;
    int* counts  = ip; ip += NN;
    int* offsets = ip; ip += NN + 1;
    int* cnt2    = ip; ip += NN;
    int* dstP    = ip; ip += NE;
    // aliases into dead phi region (phi dead after gather each layer)
    float* vnorm = phi;
    float* dotb  = phi + NN * 128;
    float* abuf  = phi + NN * 256;     // N*384

    // ---- init ----
    hipMemsetAsync(counts, 0, NN * sizeof(int), stream);
    hipMemsetAsync(cnt2, 0, NN * sizeof(int), stream);
    hipMemsetAsync(Va, 0, (size_t)NN * 384 * sizeof(float), stream);
    hipMemsetAsync(Vba, 0, (size_t)NN * 384 * sizeof(float), stream);
    hipMemsetAsync(Sbar, 0, (size_t)NN * 128 * sizeof(float), stream);
    hipMemcpyAsync(H, H_in, (size_t)NN * 128 * sizeof(float),
                   hipMemcpyDeviceToDevice, stream);

    // ---- edge CSR + geometry (2-pass, writes permuted directly) ----
    edge_count_kernel<<<(NE + 255) / 256, 256, 0, stream>>>(nbr, counts);
    scan_kernel<<<1, 1024, 0, stream>>>(counts, offsets);
    edge_geom_fill_kernel<<<(NE + 255) / 256, 256, 0, stream>>>(xyz, nbr, offsets, cnt2,
                                                                dstP, ueP, rbfP);
    build_uvcat_kernel<<<(3 * 128 * 256 + 255) / 256, 256, 0, stream>>>(updU, updV, UVcat);

    for (int l = 0; l < 3; ++l) {
        const float* W1 = msgW1 + (size_t)l * 256 * 256;
        const float* b1 = msgb1 + (size_t)l * 256;
        const float* W2 = msgW2 + (size_t)l * 256 * 640;
        const float* b2 = msgb2 + (size_t)l * 640;
        const float* dW = distW + (size_t)l * NRBF * 640;
        const float* db = distb + (size_t)l * 640;
        const float* UVl = UVcat + (size_t)l * 128 * 256;
        const float* uW1 = updW1 + (size_t)l * 256 * 128;
        const float* ub1 = updb1 + (size_t)l * 128;
        const float* uW2 = updW2 + (size_t)l * 128 * 384;
        const float* ub2 = updb2 + (size_t)l * 384;

        float *Vold, *Vnew, *Vbold, *Vbnew;
        if (l == 0)      { Vold = Va; Vnew = Vb; Vbold = Vba; Vbnew = Vbb; }
        else if (l == 1) { Vold = Vb; Vnew = Va; Vbold = Vbb; Vbnew = Vba; }
        else             { Vold = Va; Vnew = Vb; Vbold = Vba; Vbnew = Vbb; }

        // phi = silu([H|Sbar] @ W1 + b1) @ W2 + b2
        {
            dim3 g(256 / 64, (NN + 63) / 64);
            gemm3_kernel<1, 1><<<g, 256, 0, stream>>>(H, Sbar, W1, b1, X1, NN, 256, 256);
        }
        {
            dim3 g(640 / 64, (NN + 63) / 64);
            gemm3_kernel<0, 0><<<g, 256, 0, stream>>>(X1, nullptr, W2, b2, phi, NN, 256, 640);
        }

        // message gather (1 node per 256-thread block, plane-split halves)
        gather_kernel<<<NN, 256, 0, stream>>>(offsets, dstP, ueP, rbfP,
                                              phi, dW, db, Vold, Vbold,
                                              H, Sbar, Vnew, Vbnew);

        // uv2[3N x 256] = Vplanar[3N x 128] @ [U|V]
        {
            dim3 g(256 / 64, (3 * NN + 63) / 64);
            gemm3_kernel<0, 0><<<g, 256, 0, stream>>>(Vnew, nullptr, UVl, nullptr,
                                                      uv2, 3 * NN, 128, 256);
        }
        norm_kernel<<<(NN * 128 + 255) / 256, 256, 0, stream>>>(uv2, vnorm, dotb);

        // a = silu([H|v_norm] @ uW1 + ub1) @ uW2 + ub2
        {
            dim3 g(128 / 64, (NN + 63) / 64);
            gemm3_kernel<1, 1><<<g, 256, 0, stream>>>(H, vnorm, uW1, ub1, X1, NN, 256, 128);
        }
        {
            dim3 g(384 / 64, (NN + 63) / 64);
            gemm3_kernel<0, 0><<<g, 256, 0, stream>>>(X1, nullptr, uW2, ub2, abuf, NN, 128, 384);
        }

        // H += a1*dot + a2 ; V += a0*u_v
        if (l < 2)
            final_update_kernel<0><<<(NN * 128 + 255) / 256, 256, 0, stream>>>(
                abuf, dotb, uv2, H, Vnew, nullptr);
        else
            final_update_kernel<1><<<(NN * 128 + 255) / 256, 256, 0, stream>>>(
                abuf, dotb, uv2, H, Vnew, Vout);
    }
}

// Round 9
// 900.626 us; speedup vs baseline: 1.4494x; 1.0351x over previous
//
#include <hip/hip_runtime.h>
#include <math.h>

#define NN 10000
#define NE 160000
#define FDIM 128
#define NRBF 20
#define PI_F 3.14159265358979323846f
#define LDP 40  // LDS row pitch in bf16 elems (80 B -> 16B-aligned b128 rows)

typedef short bf16x8 __attribute__((ext_vector_type(8)));
typedef float f32x4 __attribute__((ext_vector_type(4)));
typedef float v2f __attribute__((ext_vector_type(2)));

__device__ __forceinline__ unsigned short f2bf_rne(float v) {
    unsigned int u = __float_as_uint(v);
    u += 0x7FFF + ((u >> 16) & 1);
    return (unsigned short)(u >> 16);
}
__device__ __forceinline__ float bf2f(unsigned short b) {
    return __uint_as_float(((unsigned int)b) << 16);
}

// ---------------------------------------------------------------------------
// Pass 1: src histogram
// ---------------------------------------------------------------------------
__global__ void edge_count_kernel(const int* __restrict__ nbr, int* __restrict__ counts)
{
    int e = blockIdx.x * blockDim.x + threadIdx.x;
    if (e >= NE) return;
    atomicAdd(&counts[nbr[2 * e]], 1);
}

// ---------------------------------------------------------------------------
// Single-block exclusive scan over counts -> offsets (N+1)
// ---------------------------------------------------------------------------
__global__ void scan_kernel(const int* __restrict__ counts, int* __restrict__ offsets)
{
    __shared__ int sd[1024];
    __shared__ int carry;
    if (threadIdx.x == 0) carry = 0;
    __syncthreads();
    for (int base = 0; base < NN; base += 1024) {
        int i = base + threadIdx.x;
        int v = (i < NN) ? counts[i] : 0;
        sd[threadIdx.x] = v;
        __syncthreads();
        for (int off = 1; off < 1024; off <<= 1) {
            int t = (threadIdx.x >= off) ? sd[threadIdx.x - off] : 0;
            __syncthreads();
            sd[threadIdx.x] += t;
            __syncthreads();
        }
        if (i < NN) offsets[i] = carry + sd[threadIdx.x] - v;
        __syncthreads();
        if (threadIdx.x == 0) carry += sd[1023];
        __syncthreads();
    }
    if (threadIdx.x == 0) offsets[NN] = carry;
}

// ---------------------------------------------------------------------------
// Pass 2: geometry into CSR-permuted slots (fp32).
// ---------------------------------------------------------------------------
__global__ void edge_geom_fill_kernel(const float* __restrict__ xyz, const int* __restrict__ nbr,
                                      const int* __restrict__ offsets, int* __restrict__ cnt2,
                                      int* __restrict__ dstP, float4* __restrict__ ueP,
                                      float* __restrict__ rbfP)
{
    int e = blockIdx.x * blockDim.x + threadIdx.x;
    if (e >= NE) return;
    int s = nbr[2 * e], d = nbr[2 * e + 1];
    float dx = xyz[3 * d + 0] - xyz[3 * s + 0];
    float dy = xyz[3 * d + 1] - xyz[3 * s + 1];
    float dz = xyz[3 * d + 2] - xyz[3 * s + 2];
    float dist = sqrtf(dx * dx + dy * dy + dz * dz);
    float inv = 1.0f / dist;
    int p = offsets[s] + atomicAdd(&cnt2[s], 1);
    dstP[p] = d;
    const float c = PI_F / 5.0f;
    float env = (dist < 5.0f) ? 0.5f * (cosf(c * dist) + 1.0f) : 0.0f;
    ueP[p] = make_float4(dx * inv, dy * inv, dz * inv, env);
#pragma unroll
    for (int k = 0; k < NRBF; k++)
        rbfP[NRBF * p + k] = sinf((float)(k + 1) * c * dist) * inv;
}

// ---------------------------------------------------------------------------
// Split fp32 -> (hi,lo) bf16 pair, elementwise.
// ---------------------------------------------------------------------------
__global__ void split_kernel(const float* __restrict__ src,
                             unsigned short* __restrict__ h,
                             unsigned short* __restrict__ l, int n)
{
    int idx = blockIdx.x * blockDim.x + threadIdx.x;
    if (idx >= n) return;
    float v = src[idx];
    unsigned short hh = f2bf_rne(v);
    h[idx] = hh;
    l[idx] = f2bf_rne(v - bf2f(hh));
}

// ---------------------------------------------------------------------------
// Build [U|V] concatenated weights (split) for the uv GEMM, all 3 layers.
// ---------------------------------------------------------------------------
__global__ void build_uvcat_kernel(const float* __restrict__ updU,
                                   const float* __restrict__ updV,
                                   unsigned short* __restrict__ h,
                                   unsigned short* __restrict__ l)
{
    int idx = blockIdx.x * blockDim.x + threadIdx.x;
    if (idx >= 3 * 128 * 256) return;
    int ly = idx / (128 * 256);
    int rem = idx % (128 * 256);
    int k = rem >> 8, j = rem & 255;
    float v = (j < 128) ? updU[(ly * 128 + k) * 128 + j]
                        : updV[(ly * 128 + k) * 128 + (j - 128)];
    unsigned short hh = f2bf_rne(v);
    h[idx] = hh;
    l[idx] = f2bf_rne(v - bf2f(hh));
}

// ---------------------------------------------------------------------------
// Split-bf16 MFMA GEMM v4. B always pre-split (Wh/Wl, row-major KxN ushort).
// ASPLIT: A pre-split (Agh/Agl, row-major MxK). else fp32 A (CAT: two halves).
// OSPLIT: epilogue writes split bf16 (Ch/Cl) instead of fp32 C.
// Block 256 thr, tile 64x64, BK=32; wave w -> 2x2 16x16x32 MFMA tiles.
// ---------------------------------------------------------------------------
template <int ACT, int CAT, int ASPLIT, int OSPLIT>
__global__ __launch_bounds__(256) void gemm4_kernel(
    const float* __restrict__ Af, const float* __restrict__ A1,
    const unsigned short* __restrict__ Agh, const unsigned short* __restrict__ Agl,
    const unsigned short* __restrict__ Wh_g, const unsigned short* __restrict__ Wl_g,
    const float* __restrict__ bias,
    float* __restrict__ C, unsigned short* __restrict__ Ch, unsigned short* __restrict__ Cl,
    int M, int K, int N)
{
    __shared__ __align__(16) unsigned short Ah[64 * LDP];
    __shared__ __align__(16) unsigned short Al[64 * LDP];
    __shared__ __align__(16) unsigned short Bh[64 * LDP];
    __shared__ __align__(16) unsigned short Bl[64 * LDP];

    int tid = threadIdx.x;
    int row0 = blockIdx.y * 64, col0 = blockIdx.x * 64;
    int lane = tid & 63, wave = tid >> 6;
    int mb = (wave & 1) * 32, nb = (wave >> 1) * 32;
    int lm = lane & 15, quad = lane >> 4;

    f32x4 acc[2][2] = {};

    int ra = tid >> 2, kq = tid & 3;
    int kr = tid >> 3, nq = tid & 7;

    for (int k0 = 0; k0 < K; k0 += 32) {
        // ---- stage A ----
        {
            int ar = row0 + ra;
            if (ASPLIT) {
                ushort4 h0 = {0, 0, 0, 0}, h1 = {0, 0, 0, 0};
                ushort4 l0 = {0, 0, 0, 0}, l1 = {0, 0, 0, 0};
                if (ar < M) {
                    const unsigned short* bh = Agh + (size_t)ar * K + k0;
                    const unsigned short* bl = Agl + (size_t)ar * K + k0;
                    h0 = *(const ushort4*)(bh + kq * 4);
                    h1 = *(const ushort4*)(bh + kq * 4 + 16);
                    l0 = *(const ushort4*)(bl + kq * 4);
                    l1 = *(const ushort4*)(bl + kq * 4 + 16);
                }
                *(ushort4*)&Ah[ra * LDP + kq * 4]      = h0;
                *(ushort4*)&Al[ra * LDP + kq * 4]      = l0;
                *(ushort4*)&Ah[ra * LDP + kq * 4 + 16] = h1;
                *(ushort4*)&Al[ra * LDP + kq * 4 + 16] = l1;
            } else {
                float4 a0 = make_float4(0.f, 0.f, 0.f, 0.f);
                float4 a1 = make_float4(0.f, 0.f, 0.f, 0.f);
                if (ar < M) {
                    const float* Ab;
                    if (CAT) Ab = (k0 < 128) ? Af + (size_t)ar * 128 + k0
                                             : A1 + (size_t)ar * 128 + (k0 - 128);
                    else     Ab = Af + (size_t)ar * K + k0;
                    a0 = *(const float4*)(Ab + kq * 4);
                    a1 = *(const float4*)(Ab + kq * 4 + 16);
                }
                float v0[4] = {a0.x, a0.y, a0.z, a0.w};
                float v1[4] = {a1.x, a1.y, a1.z, a1.w};
                ushort4 h0, l0, h1, l1;
                unsigned short* hp0 = (unsigned short*)&h0;
                unsigned short* lp0 = (unsigned short*)&l0;
                unsigned short* hp1 = (unsigned short*)&h1;
                unsigned short* lp1 = (unsigned short*)&l1;
#pragma unroll
                for (int i = 0; i < 4; i++) {
                    unsigned short h = f2bf_rne(v0[i]);
                    hp0[i] = h; lp0[i] = f2bf_rne(v0[i] - bf2f(h));
                    unsigned short g = f2bf_rne(v1[i]);
                    hp1[i] = g; lp1[i] = f2bf_rne(v1[i] - bf2f(g));
                }
                *(ushort4*)&Ah[ra * LDP + kq * 4]      = h0;
                *(ushort4*)&Al[ra * LDP + kq * 4]      = l0;
                *(ushort4*)&Ah[ra * LDP + kq * 4 + 16] = h1;
                *(ushort4*)&Al[ra * LDP + kq * 4 + 16] = l1;
            }
        }
        // ---- stage B (pre-split), transpose into [n][k] ----
        {
            const unsigned short* Wbh = Wh_g + (size_t)(k0 + kr) * N + col0;
            const unsigned short* Wbl = Wl_g + (size_t)(k0 + kr) * N + col0;
            ushort4 h0 = *(const ushort4*)(Wbh + nq * 4);
            ushort4 h1 = *(const ushort4*)(Wbh + nq * 4 + 32);
            ushort4 l0 = *(const ushort4*)(Wbl + nq * 4);
            ushort4 l1 = *(const ushort4*)(Wbl + nq * 4 + 32);
            const unsigned short* hp0 = (const unsigned short*)&h0;
            const unsigned short* hp1 = (const unsigned short*)&h1;
            const unsigned short* lp0 = (const unsigned short*)&l0;
            const unsigned short* lp1 = (const unsigned short*)&l1;
#pragma unroll
            for (int i = 0; i < 4; i++) {
                int n = nq * 4 + i;
                Bh[n * LDP + kr] = hp0[i];
                Bl[n * LDP + kr] = lp0[i];
                Bh[(n + 32) * LDP + kr] = hp1[i];
                Bl[(n + 32) * LDP + kr] = lp1[i];
            }
        }
        __syncthreads();
        bf16x8 fah[2], fal[2], fbh[2], fbl[2];
#pragma unroll
        for (int mt = 0; mt < 2; mt++) {
            int r = mb + mt * 16 + lm;
            fah[mt] = *(const bf16x8*)&Ah[r * LDP + quad * 8];
            fal[mt] = *(const bf16x8*)&Al[r * LDP + quad * 8];
        }
#pragma unroll
        for (int nt = 0; nt < 2; nt++) {
            int n = nb + nt * 16 + lm;
            fbh[nt] = *(const bf16x8*)&Bh[n * LDP + quad * 8];
            fbl[nt] = *(const bf16x8*)&Bl[n * LDP + quad * 8];
        }
#pragma unroll
        for (int mt = 0; mt < 2; mt++)
#pragma unroll
            for (int nt = 0; nt < 2; nt++) {
                acc[mt][nt] = __builtin_amdgcn_mfma_f32_16x16x32_bf16(
                    fah[mt], fbh[nt], acc[mt][nt], 0, 0, 0);
                acc[mt][nt] = __builtin_amdgcn_mfma_f32_16x16x32_bf16(
                    fah[mt], fbl[nt], acc[mt][nt], 0, 0, 0);
                acc[mt][nt] = __builtin_amdgcn_mfma_f32_16x16x32_bf16(
                    fal[mt], fbh[nt], acc[mt][nt], 0, 0, 0);
            }
        __syncthreads();
    }
#pragma unroll
    for (int mt = 0; mt < 2; mt++)
#pragma unroll
        for (int nt = 0; nt < 2; nt++) {
            int c = col0 + nb + nt * 16 + lm;
            float bv = bias ? bias[c] : 0.f;
#pragma unroll
            for (int reg = 0; reg < 4; reg++) {
                int r = row0 + mb + mt * 16 + quad * 4 + reg;
                if (r >= M) continue;
                float v = acc[mt][nt][reg] + bv;
                if (ACT) v = v / (1.0f + expf(-v));
                if (OSPLIT) {
                    unsigned short h = f2bf_rne(v);
                    Ch[(size_t)r * N + c] = h;
                    Cl[(size_t)r * N + c] = f2bf_rne(v - bf2f(h));
                } else {
                    C[(size_t)r * N + c] = v;
                }
            }
        }
}

// ---------------------------------------------------------------------------
// Gather, plane-split (R8 structure) + packed v_pk_fma w-dot.
// L0=1: V/Vbar are all-zero -> skip scattered V reads and own-row base.
// ---------------------------------------------------------------------------
template <int L0>
__global__ __launch_bounds__(256, 4) void gather_kernel(
    const int* __restrict__ offsets, const int* __restrict__ dstP,
    const float4* __restrict__ ueP, const float* __restrict__ rbfP,
    const float* __restrict__ phi,
    const float* __restrict__ distW, const float* __restrict__ distb,
    const float* __restrict__ Vold, const float* __restrict__ Vbold,
    float* __restrict__ H, float* __restrict__ Sbar,
    float* __restrict__ Vnew, float* __restrict__ Vbnew)
{
    int n = blockIdx.x;
    int t = threadIdx.x;
    int half = t >> 7;          // wave-uniform
    int f = t & 127;
    int po = half * 256;

    // wv2[q*3+c] = {distW[2q, po+c*128+f], distW[2q+1, po+c*128+f]}
    v2f wv2[30];
#pragma unroll
    for (int q = 0; q < 10; q++)
#pragma unroll
        for (int c = 0; c < 3; c++) {
            wv2[q * 3 + c].x = distW[(2 * q) * 640 + po + c * 128 + f];
            wv2[q * 3 + c].y = distW[(2 * q + 1) * 640 + po + c * 128 + f];
        }
#pragma unroll
    for (int i = 0; i < 30; i++) asm volatile("" : "+v"(wv2[i]));

    float bA = distb[po + f], bB = distb[po + 128 + f], bC = distb[po + 256 + f];

    const float* Vsel = half ? Vbold : Vold;

    float sacc = 0.f, acc0 = 0.f, acc1 = 0.f, acc2 = 0.f;
    int e0 = offsets[n], e1 = offsets[n + 1];
    for (int p = e0; p < e1; ++p) {
        int d = dstP[p];
        float4 ue = ueP[p];
        float r[NRBF];
#pragma unroll
        for (int q = 0; q < NRBF / 4; q++) {
            float4 rv = *(const float4*)&rbfP[NRBF * p + 4 * q];
            r[4 * q + 0] = rv.x; r[4 * q + 1] = rv.y;
            r[4 * q + 2] = rv.z; r[4 * q + 3] = rv.w;
        }
        v2f aA = {0.f, 0.f}, aB = {0.f, 0.f}, aC = {0.f, 0.f};
#pragma unroll
        for (int q = 0; q < 10; q++) {
            v2f r2; r2.x = r[2 * q]; r2.y = r[2 * q + 1];
            aA += r2 * wv2[q * 3 + 0];
            aB += r2 * wv2[q * 3 + 1];
            aC += r2 * wv2[q * 3 + 2];
        }
        float ev = ue.w;
        float wA = (aA.x + aA.y + bA) * ev;
        float wB = (aB.x + aB.y + bB) * ev;
        float wC = (aC.x + aC.y + bC) * ev;
        const float* ph = phi + (size_t)d * 640 + po;
        float iA = ph[f] * wA;
        float iB = ph[128 + f] * wB;
        float iC = ph[256 + f] * wC;
        // half0: iA=gate_v, iB=ds,    iC=dir
        // half1: iA=dir,    iB=dsbar, iC=gate_vbar
        float dir = half ? iA : iC;
        sacc += iB;
        if (L0) {
            acc0 += dir * ue.x;
            acc1 += dir * ue.y;
            acc2 += dir * ue.z;
        } else {
            float gate = half ? iC : iA;
            const float* vd = Vsel + (size_t)d * 384;
            acc0 += dir * ue.x + gate * vd[f];
            acc1 += dir * ue.y + gate * vd[128 + f];
            acc2 += dir * ue.z + gate * vd[256 + f];
        }
    }
    if (half == 0) H[n * 128 + f] += sacc;
    else           Sbar[n * 128 + f] += sacc;
    float* vn = (half ? Vbnew : Vnew) + (size_t)n * 384;
    if (L0) {
        vn[f] = acc0; vn[128 + f] = acc1; vn[256 + f] = acc2;
    } else {
        const float* vo = Vsel + (size_t)n * 384;
        vn[f]       = vo[f]       + acc0;
        vn[128 + f] = vo[128 + f] + acc1;
        vn[256 + f] = vo[256 + f] + acc2;
    }
}

// ---------------------------------------------------------------------------
// norm/dot from fused uv2 [3N x 256]: node n rows n*3+c; u col g, v col 128+g.
// ---------------------------------------------------------------------------
__global__ void norm_kernel(const float* __restrict__ uv2,
                            float* __restrict__ vnorm, float* __restrict__ dotb)
{
    int idx = blockIdx.x * blockDim.x + threadIdx.x;
    if (idx >= NN * 128) return;
    int n = idx >> 7, g = idx & 127;
    const float* base = uv2 + (size_t)n * 768;
    float u0 = base[g],       u1 = base[256 + g], u2 = base[512 + g];
    float v0 = base[128 + g], v1 = base[384 + g], v2 = base[640 + g];
    dotb[idx] = u0 * v0 + u1 * v1 + u2 * v2;
    vnorm[idx] = sqrtf(v0 * v0 + v1 * v1 + v2 * v2 + 1e-15f);
}

// ---------------------------------------------------------------------------
// Final per-layer update: H += a1*dot + a2 ; V += a0*u_v (u from uv2).
// ---------------------------------------------------------------------------
template <int LAST>
__global__ void final_update_kernel(const float* __restrict__ a,
                                    const float* __restrict__ dotb,
                                    const float* __restrict__ uv2,
                                    float* __restrict__ H,
                                    float* __restrict__ Vplanar,
                                    float* __restrict__ Vout)
{
    int idx = blockIdx.x * blockDim.x + threadIdx.x;
    if (idx >= NN * 128) return;
    int n = idx >> 7, g = idx & 127;
    float a0 = a[n * 384 + g];
    float a1 = a[n * 384 + 128 + g];
    float a2 = a[n * 384 + 256 + g];
    H[idx] += a1 * dotb[idx] + a2;
    float* vp = Vplanar + (size_t)n * 384;
    const float* ub = uv2 + (size_t)n * 768;
    float v0 = vp[g]       + a0 * ub[g];
    float v1 = vp[128 + g] + a0 * ub[256 + g];
    float v2 = vp[256 + g] + a0 * ub[512 + g];
    if (LAST) {
        float* o = Vout + (size_t)n * 384 + g * 3;
        o[0] = v0; o[1] = v1; o[2] = v2;
    } else {
        vp[g] = v0; vp[128 + g] = v1; vp[256 + g] = v2;
    }
}

// ---------------------------------------------------------------------------
extern "C" void kernel_launch(void* const* d_in, const int* in_sizes, int n_in,
                              void* d_out, int out_size, void* d_ws, size_t ws_size,
                              hipStream_t stream)
{
    const float* xyz    = (const float*)d_in[0];
    const int*   nbr    = (const int*)d_in[1];
    const float* H_in   = (const float*)d_in[3];
    const float* msgW1  = (const float*)d_in[4];
    const float* msgb1  = (const float*)d_in[5];
    const float* msgW2  = (const float*)d_in[6];
    const float* msgb2  = (const float*)d_in[7];
    const float* distW  = (const float*)d_in[8];
    const float* distb  = (const float*)d_in[9];
    const float* updU   = (const float*)d_in[10];
    const float* updV   = (const float*)d_in[11];
    const float* updW1  = (const float*)d_in[12];
    const float* updb1  = (const float*)d_in[13];
    const float* updW2  = (const float*)d_in[14];
    const float* updb2  = (const float*)d_in[15];

    float* out  = (float*)d_out;
    float* H    = out;                 // N*128
    float* Vout = out + NN * 128;      // N*384 interleaved (n,f,3)

    // ---- workspace carve ----
    float* f = (float*)d_ws;
    float* Va   = f; f += NN * 384;    // planar V buffers
    float* Vb   = f; f += NN * 384;
    float* Vba  = f; f += NN * 384;
    float* Vbb  = f; f += NN * 384;
    float* Sbar = f; f += NN * 128;
    float* phi  = f; f += NN * 640;
    float* uv2  = f; f += NN * 768;    // [3N x 256] fused u_v|v_v
    float4* ueP = (float4*)f; f += NE * 4;
    float* rbfP  = f; f += NE * NRBF;
    unsigned short* us = (unsigned short*)f;
    unsigned short* X1h = us; us += NN * 256;
    unsigned short* X1l = us; us += NN * 256;
    unsigned short* W1h = us; us += 3 * 256 * 256;
    unsigned short* W1l = us; us += 3 * 256 * 256;
    unsigned short* W2h = us; us += 3 * 256 * 640;
    unsigned short* W2l = us; us += 3 * 256 * 640;
    unsigned short* UVh = us; us += 3 * 128 * 256;
    unsigned short* UVl = us; us += 3 * 128 * 256;
    unsigned short* uW1h = us; us += 3 * 256 * 128;
    unsigned short* uW1l = us; us += 3 * 256 * 128;
    unsigned short* uW2h = us; us += 3 * 128 * 384;
    unsigned short* uW2l = us; us += 3 * 128 * 384;
    int* ip = (int*)(((size_t)us + 15) & ~(size_t)15);
    int* counts  = ip; ip += NN;
    int* offsets = ip; ip += NN + 1;
    int* cnt2    = ip; ip += NN;
    int* dstP    = ip; ip += NE;
    // aliases into dead phi region (phi dead after gather each layer)
    float* vnorm = phi;
    float* dotb  = phi + NN * 128;
    float* abuf  = phi + NN * 256;     // N*384

    // ---- init ----
    hipMemsetAsync(counts, 0, NN * sizeof(int), stream);
    hipMemsetAsync(cnt2, 0, NN * sizeof(int), stream);
    hipMemsetAsync(Sbar, 0, (size_t)NN * 128 * sizeof(float), stream);
    hipMemcpyAsync(H, H_in, (size_t)NN * 128 * sizeof(float),
                   hipMemcpyDeviceToDevice, stream);

    // ---- edge CSR + geometry + weight pre-split ----
    edge_count_kernel<<<(NE + 255) / 256, 256, 0, stream>>>(nbr, counts);
    scan_kernel<<<1, 1024, 0, stream>>>(counts, offsets);
    edge_geom_fill_kernel<<<(NE + 255) / 256, 256, 0, stream>>>(xyz, nbr, offsets, cnt2,
                                                                dstP, ueP, rbfP);
    split_kernel<<<(3 * 256 * 256 + 255) / 256, 256, 0, stream>>>(msgW1, W1h, W1l, 3 * 256 * 256);
    split_kernel<<<(3 * 256 * 640 + 255) / 256, 256, 0, stream>>>(msgW2, W2h, W2l, 3 * 256 * 640);
    split_kernel<<<(3 * 256 * 128 + 255) / 256, 256, 0, stream>>>(updW1, uW1h, uW1l, 3 * 256 * 128);
    split_kernel<<<(3 * 128 * 384 + 255) / 256, 256, 0, stream>>>(updW2, uW2h, uW2l, 3 * 128 * 384);
    build_uvcat_kernel<<<(3 * 128 * 256 + 255) / 256, 256, 0, stream>>>(updU, updV, UVh, UVl);

    for (int l = 0; l < 3; ++l) {
        const float* b1 = msgb1 + (size_t)l * 256;
        const float* b2 = msgb2 + (size_t)l * 640;
        const float* dW = distW + (size_t)l * NRBF * 640;
        const float* db = distb + (size_t)l * 640;
        const float* ub1 = updb1 + (size_t)l * 128;
        const float* ub2 = updb2 + (size_t)l * 384;
        const unsigned short *w1h = W1h + (size_t)l * 256 * 256, *w1l = W1l + (size_t)l * 256 * 256;
        const unsigned short *w2h = W2h + (size_t)l * 256 * 640, *w2l = W2l + (size_t)l * 256 * 640;
        const unsigned short *uvh = UVh + (size_t)l * 128 * 256, *uvl = UVl + (size_t)l * 128 * 256;
        const unsigned short *u1h = uW1h + (size_t)l * 256 * 128, *u1l = uW1l + (size_t)l * 256 * 128;
        const unsigned short *u2h = uW2h + (size_t)l * 128 * 384, *u2l = uW2l + (size_t)l * 128 * 384;

        float *Vold, *Vnew, *Vbold, *Vbnew;
        if (l == 0)      { Vold = Va; Vnew = Vb; Vbold = Vba; Vbnew = Vbb; }
        else if (l == 1) { Vold = Vb; Vnew = Va; Vbold = Vbb; Vbnew = Vba; }
        else             { Vold = Va; Vnew = Vb; Vbold = Vba; Vbnew = Vbb; }

        // X1 = silu([H|Sbar] @ W1 + b1)  (split-bf16 output)
        {
            dim3 g(256 / 64, (NN + 63) / 64);
            gemm4_kernel<1, 1, 0, 1><<<g, 256, 0, stream>>>(
                H, Sbar, nullptr, nullptr, w1h, w1l, b1,
                nullptr, X1h, X1l, NN, 256, 256);
        }
        // phi = X1 @ W2 + b2  (fp32 output)
        {
            dim3 g(640 / 64, (NN + 63) / 64);
            gemm4_kernel<0, 0, 1, 0><<<g, 256, 0, stream>>>(
                nullptr, nullptr, X1h, X1l, w2h, w2l, b2,
                phi, nullptr, nullptr, NN, 256, 640);
        }

        // message gather
        if (l == 0)
            gather_kernel<1><<<NN, 256, 0, stream>>>(offsets, dstP, ueP, rbfP,
                                                     phi, dW, db, Vold, Vbold,
                                                     H, Sbar, Vnew, Vbnew);
        else
            gather_kernel<0><<<NN, 256, 0, stream>>>(offsets, dstP, ueP, rbfP,
                                                     phi, dW, db, Vold, Vbold,
                                                     H, Sbar, Vnew, Vbnew);

        // uv2[3N x 256] = Vplanar[3N x 128] @ [U|V]
        {
            dim3 g(256 / 64, (3 * NN + 63) / 64);
            gemm4_kernel<0, 0, 0, 0><<<g, 256, 0, stream>>>(
                Vnew, nullptr, nullptr, nullptr, uvh, uvl, nullptr,
                uv2, nullptr, nullptr, 3 * NN, 128, 256);
        }
        norm_kernel<<<(NN * 128 + 255) / 256, 256, 0, stream>>>(uv2, vnorm, dotb);

        // X1 = silu([H|vnorm] @ uW1 + ub1)  (split output, 128 wide)
        {
            dim3 g(128 / 64, (NN + 63) / 64);
            gemm4_kernel<1, 1, 0, 1><<<g, 256, 0, stream>>>(
                H, vnorm, nullptr, nullptr, u1h, u1l, ub1,
                nullptr, X1h, X1l, NN, 256, 128);
        }
        // abuf = X1 @ uW2 + ub2
        {
            dim3 g(384 / 64, (NN + 63) / 64);
            gemm4_kernel<0, 0, 1, 0><<<g, 256, 0, stream>>>(
                nullptr, nullptr, X1h, X1l, u2h, u2l, ub2,
                abuf, nullptr, nullptr, NN, 128, 384);
        }

        // H += a1*dot + a2 ; V += a0*u_v
        if (l < 2)
            final_update_kernel<0><<<(NN * 128 + 255) / 256, 256, 0, stream>>>(
                abuf, dotb, uv2, H, Vnew, nullptr);
        else
            final_update_kernel<1><<<(NN * 128 + 255) / 256, 256, 0, stream>>>(
                abuf, dotb, uv2, H, Vnew, Vout);
    }
}

// Round 10
// 869.240 us; speedup vs baseline: 1.5017x; 1.0361x over previous
//
#include <hip/hip_runtime.h>
#include <math.h>

#define NN 10000
#define NE 160000
#define FDIM 128
#define NRBF 20
#define PI_F 3.14159265358979323846f
#define LDP 40  // LDS row pitch in bf16 elems (80 B -> 16B-aligned b128 rows)

typedef short bf16x8 __attribute__((ext_vector_type(8)));
typedef float f32x4 __attribute__((ext_vector_type(4)));
typedef float v2f __attribute__((ext_vector_type(2)));

__device__ __forceinline__ unsigned short f2bf_rne(float v) {
    unsigned int u = __float_as_uint(v);
    u += 0x7FFF + ((u >> 16) & 1);
    return (unsigned short)(u >> 16);
}
__device__ __forceinline__ float bf2f(unsigned short b) {
    return __uint_as_float(((unsigned int)b) << 16);
}

// ---------------------------------------------------------------------------
// Pass 1: src histogram
// ---------------------------------------------------------------------------
__global__ void edge_count_kernel(const int* __restrict__ nbr, int* __restrict__ counts)
{
    int e = blockIdx.x * blockDim.x + threadIdx.x;
    if (e >= NE) return;
    atomicAdd(&counts[nbr[2 * e]], 1);
}

// ---------------------------------------------------------------------------
// Single-block exclusive scan over counts -> offsets (N+1)
// ---------------------------------------------------------------------------
__global__ void scan_kernel(const int* __restrict__ counts, int* __restrict__ offsets)
{
    __shared__ int sd[1024];
    __shared__ int carry;
    if (threadIdx.x == 0) carry = 0;
    __syncthreads();
    for (int base = 0; base < NN; base += 1024) {
        int i = base + threadIdx.x;
        int v = (i < NN) ? counts[i] : 0;
        sd[threadIdx.x] = v;
        __syncthreads();
        for (int off = 1; off < 1024; off <<= 1) {
            int t = (threadIdx.x >= off) ? sd[threadIdx.x - off] : 0;
            __syncthreads();
            sd[threadIdx.x] += t;
            __syncthreads();
        }
        if (i < NN) offsets[i] = carry + sd[threadIdx.x] - v;
        __syncthreads();
        if (threadIdx.x == 0) carry += sd[1023];
        __syncthreads();
    }
    if (threadIdx.x == 0) offsets[NN] = carry;
}

// ---------------------------------------------------------------------------
// Pass 2: geometry into CSR-permuted slots (fp32).
// ---------------------------------------------------------------------------
__global__ void edge_geom_fill_kernel(const float* __restrict__ xyz, const int* __restrict__ nbr,
                                      const int* __restrict__ offsets, int* __restrict__ cnt2,
                                      int* __restrict__ dstP, float4* __restrict__ ueP,
                                      float* __restrict__ rbfP)
{
    int e = blockIdx.x * blockDim.x + threadIdx.x;
    if (e >= NE) return;
    int s = nbr[2 * e], d = nbr[2 * e + 1];
    float dx = xyz[3 * d + 0] - xyz[3 * s + 0];
    float dy = xyz[3 * d + 1] - xyz[3 * s + 1];
    float dz = xyz[3 * d + 2] - xyz[3 * s + 2];
    float dist = sqrtf(dx * dx + dy * dy + dz * dz);
    float inv = 1.0f / dist;
    int p = offsets[s] + atomicAdd(&cnt2[s], 1);
    dstP[p] = d;
    const float c = PI_F / 5.0f;
    float env = (dist < 5.0f) ? 0.5f * (cosf(c * dist) + 1.0f) : 0.0f;
    ueP[p] = make_float4(dx * inv, dy * inv, dz * inv, env);
#pragma unroll
    for (int k = 0; k < NRBF; k++)
        rbfP[NRBF * p + k] = sinf((float)(k + 1) * c * dist) * inv;
}

// ---------------------------------------------------------------------------
// Transpose + split: src [3][K][N] fp32 -> th/tl [3][N][K] bf16 pair.
// ---------------------------------------------------------------------------
__global__ void tsplit_kernel(const float* __restrict__ src,
                              unsigned short* __restrict__ th,
                              unsigned short* __restrict__ tl, int K, int N)
{
    int idx = blockIdx.x * blockDim.x + threadIdx.x;
    int tot = 3 * K * N;
    if (idx >= tot) return;
    int l = idx / (K * N);
    int rem = idx - l * (K * N);
    int k = rem / N, n = rem - k * N;
    float v = src[idx];
    unsigned short hh = f2bf_rne(v);
    size_t o = (size_t)l * K * N + (size_t)n * K + k;
    th[o] = hh;
    tl[o] = f2bf_rne(v - bf2f(hh));
}

// ---------------------------------------------------------------------------
// Build transposed+split [U|V]: out [3][256][128] (n-major, k inner).
// ---------------------------------------------------------------------------
__global__ void build_uvcat_t_kernel(const float* __restrict__ updU,
                                     const float* __restrict__ updV,
                                     unsigned short* __restrict__ th,
                                     unsigned short* __restrict__ tl)
{
    int idx = blockIdx.x * blockDim.x + threadIdx.x;
    if (idx >= 3 * 128 * 256) return;
    int ly = idx / (128 * 256);
    int rem = idx % (128 * 256);
    int k = rem >> 8, j = rem & 255;
    float v = (j < 128) ? updU[(ly * 128 + k) * 128 + j]
                        : updV[(ly * 128 + k) * 128 + (j - 128)];
    unsigned short hh = f2bf_rne(v);
    size_t o = (size_t)ly * 128 * 256 + (size_t)j * 128 + k;
    th[o] = hh;
    tl[o] = f2bf_rne(v - bf2f(hh));
}

// ---------------------------------------------------------------------------
// Split-bf16 MFMA GEMM v5. B pre-split AND pre-transposed: Wth/Wtl [N][K].
// ASPLIT: A pre-split row-major [M][K]. else fp32 A (CAT: two 128 halves).
// OSPLIT: epilogue writes split bf16 (Ch/Cl row-major [M][N]).
// Block 256 thr, tile 64x64, BK=32. Staging: one b128 ld + one b128 LDS st
// per array per thread per K-step (no scattered LDS writes).
// ---------------------------------------------------------------------------
template <int ACT, int CAT, int ASPLIT, int OSPLIT>
__global__ __launch_bounds__(256) void gemm5_kernel(
    const float* __restrict__ Af, const float* __restrict__ A1,
    const unsigned short* __restrict__ Agh, const unsigned short* __restrict__ Agl,
    const unsigned short* __restrict__ Wth, const unsigned short* __restrict__ Wtl,
    const float* __restrict__ bias,
    float* __restrict__ C, unsigned short* __restrict__ Ch, unsigned short* __restrict__ Cl,
    int M, int K, int N)
{
    __shared__ __align__(16) unsigned short Ah[64 * LDP];
    __shared__ __align__(16) unsigned short Al[64 * LDP];
    __shared__ __align__(16) unsigned short Bh[64 * LDP];
    __shared__ __align__(16) unsigned short Bl[64 * LDP];

    int tid = threadIdx.x;
    int row0 = blockIdx.y * 64, col0 = blockIdx.x * 64;
    int lane = tid & 63, wave = tid >> 6;
    int mb = (wave & 1) * 32, nb = (wave >> 1) * 32;
    int lm = lane & 15, quad = lane >> 4;

    f32x4 acc[2][2] = {};

    int sm = tid >> 2;           // 0..63: A row / B out-col
    int sk = (tid & 3) * 8;      // 0,8,16,24: k offset (8 elems)

    for (int k0 = 0; k0 < K; k0 += 32) {
        // ---- stage A: 64 rows x 32 k ----
        {
            int ar = row0 + sm;
            if (ASPLIT) {
                uint4 h = {0, 0, 0, 0}, l = {0, 0, 0, 0};
                if (ar < M) {
                    h = *(const uint4*)(Agh + (size_t)ar * K + k0 + sk);
                    l = *(const uint4*)(Agl + (size_t)ar * K + k0 + sk);
                }
                *(uint4*)&Ah[sm * LDP + sk] = h;
                *(uint4*)&Al[sm * LDP + sk] = l;
            } else {
                float4 a0 = make_float4(0.f, 0.f, 0.f, 0.f);
                float4 a1 = make_float4(0.f, 0.f, 0.f, 0.f);
                if (ar < M) {
                    int kk = k0 + sk;
                    const float* Ab;
                    if (CAT) Ab = (kk < 128) ? Af + (size_t)ar * 128 + kk
                                             : A1 + (size_t)ar * 128 + (kk - 128);
                    else     Ab = Af + (size_t)ar * K + kk;
                    a0 = *(const float4*)Ab;
                    a1 = *(const float4*)(Ab + 4);
                }
                float v[8] = {a0.x, a0.y, a0.z, a0.w, a1.x, a1.y, a1.z, a1.w};
                unsigned short hs[8], ls[8];
#pragma unroll
                for (int i = 0; i < 8; i++) {
                    unsigned short h = f2bf_rne(v[i]);
                    hs[i] = h; ls[i] = f2bf_rne(v[i] - bf2f(h));
                }
                *(uint4*)&Ah[sm * LDP + sk] = *(uint4*)hs;
                *(uint4*)&Al[sm * LDP + sk] = *(uint4*)ls;
            }
        }
        // ---- stage B: 64 out-cols x 32 k (already [n][k]) ----
        {
            size_t o = (size_t)(col0 + sm) * K + k0 + sk;
            uint4 h = *(const uint4*)(Wth + o);
            uint4 l = *(const uint4*)(Wtl + o);
            *(uint4*)&Bh[sm * LDP + sk] = h;
            *(uint4*)&Bl[sm * LDP + sk] = l;
        }
        __syncthreads();
        bf16x8 fah[2], fal[2], fbh[2], fbl[2];
#pragma unroll
        for (int mt = 0; mt < 2; mt++) {
            int r = mb + mt * 16 + lm;
            fah[mt] = *(const bf16x8*)&Ah[r * LDP + quad * 8];
            fal[mt] = *(const bf16x8*)&Al[r * LDP + quad * 8];
        }
#pragma unroll
        for (int nt = 0; nt < 2; nt++) {
            int n = nb + nt * 16 + lm;
            fbh[nt] = *(const bf16x8*)&Bh[n * LDP + quad * 8];
            fbl[nt] = *(const bf16x8*)&Bl[n * LDP + quad * 8];
        }
#pragma unroll
        for (int mt = 0; mt < 2; mt++)
#pragma unroll
            for (int nt = 0; nt < 2; nt++) {
                acc[mt][nt] = __builtin_amdgcn_mfma_f32_16x16x32_bf16(
                    fah[mt], fbh[nt], acc[mt][nt], 0, 0, 0);
                acc[mt][nt] = __builtin_amdgcn_mfma_f32_16x16x32_bf16(
                    fah[mt], fbl[nt], acc[mt][nt], 0, 0, 0);
                acc[mt][nt] = __builtin_amdgcn_mfma_f32_16x16x32_bf16(
                    fal[mt], fbh[nt], acc[mt][nt], 0, 0, 0);
            }
        __syncthreads();
    }
#pragma unroll
    for (int mt = 0; mt < 2; mt++)
#pragma unroll
        for (int nt = 0; nt < 2; nt++) {
            int c = col0 + nb + nt * 16 + lm;
            float bv = bias ? bias[c] : 0.f;
#pragma unroll
            for (int reg = 0; reg < 4; reg++) {
                int r = row0 + mb + mt * 16 + quad * 4 + reg;
                if (r >= M) continue;
                float v = acc[mt][nt][reg] + bv;
                if (ACT) v = v / (1.0f + expf(-v));
                if (OSPLIT) {
                    unsigned short h = f2bf_rne(v);
                    Ch[(size_t)r * N + c] = h;
                    Cl[(size_t)r * N + c] = f2bf_rne(v - bf2f(h));
                } else {
                    C[(size_t)r * N + c] = v;
                }
            }
        }
}

// ---------------------------------------------------------------------------
// Gather (R9, PROTECTED — byte-identical): plane-split halves, packed w-dot,
// distW pinned via opaque asm. L0=1 skips zero V/Vbar.
// ---------------------------------------------------------------------------
template <int L0>
__global__ __launch_bounds__(256, 4) void gather_kernel(
    const int* __restrict__ offsets, const int* __restrict__ dstP,
    const float4* __restrict__ ueP, const float* __restrict__ rbfP,
    const float* __restrict__ phi,
    const float* __restrict__ distW, const float* __restrict__ distb,
    const float* __restrict__ Vold, const float* __restrict__ Vbold,
    float* __restrict__ H, float* __restrict__ Sbar,
    float* __restrict__ Vnew, float* __restrict__ Vbnew)
{
    int n = blockIdx.x;
    int t = threadIdx.x;
    int half = t >> 7;          // wave-uniform
    int f = t & 127;
    int po = half * 256;

    v2f wv2[30];
#pragma unroll
    for (int q = 0; q < 10; q++)
#pragma unroll
        for (int c = 0; c < 3; c++) {
            wv2[q * 3 + c].x = distW[(2 * q) * 640 + po + c * 128 + f];
            wv2[q * 3 + c].y = distW[(2 * q + 1) * 640 + po + c * 128 + f];
        }
#pragma unroll
    for (int i = 0; i < 30; i++) asm volatile("" : "+v"(wv2[i]));

    float bA = distb[po + f], bB = distb[po + 128 + f], bC = distb[po + 256 + f];

    const float* Vsel = half ? Vbold : Vold;

    float sacc = 0.f, acc0 = 0.f, acc1 = 0.f, acc2 = 0.f;
    int e0 = offsets[n], e1 = offsets[n + 1];
    for (int p = e0; p < e1; ++p) {
        int d = dstP[p];
        float4 ue = ueP[p];
        float r[NRBF];
#pragma unroll
        for (int q = 0; q < NRBF / 4; q++) {
            float4 rv = *(const float4*)&rbfP[NRBF * p + 4 * q];
            r[4 * q + 0] = rv.x; r[4 * q + 1] = rv.y;
            r[4 * q + 2] = rv.z; r[4 * q + 3] = rv.w;
        }
        v2f aA = {0.f, 0.f}, aB = {0.f, 0.f}, aC = {0.f, 0.f};
#pragma unroll
        for (int q = 0; q < 10; q++) {
            v2f r2; r2.x = r[2 * q]; r2.y = r[2 * q + 1];
            aA += r2 * wv2[q * 3 + 0];
            aB += r2 * wv2[q * 3 + 1];
            aC += r2 * wv2[q * 3 + 2];
        }
        float ev = ue.w;
        float wA = (aA.x + aA.y + bA) * ev;
        float wB = (aB.x + aB.y + bB) * ev;
        float wC = (aC.x + aC.y + bC) * ev;
        const float* ph = phi + (size_t)d * 640 + po;
        float iA = ph[f] * wA;
        float iB = ph[128 + f] * wB;
        float iC = ph[256 + f] * wC;
        float dir = half ? iA : iC;
        sacc += iB;
        if (L0) {
            acc0 += dir * ue.x;
            acc1 += dir * ue.y;
            acc2 += dir * ue.z;
        } else {
            float gate = half ? iC : iA;
            const float* vd = Vsel + (size_t)d * 384;
            acc0 += dir * ue.x + gate * vd[f];
            acc1 += dir * ue.y + gate * vd[128 + f];
            acc2 += dir * ue.z + gate * vd[256 + f];
        }
    }
    if (half == 0) H[n * 128 + f] += sacc;
    else           Sbar[n * 128 + f] += sacc;
    float* vn = (half ? Vbnew : Vnew) + (size_t)n * 384;
    if (L0) {
        vn[f] = acc0; vn[128 + f] = acc1; vn[256 + f] = acc2;
    } else {
        const float* vo = Vsel + (size_t)n * 384;
        vn[f]       = vo[f]       + acc0;
        vn[128 + f] = vo[128 + f] + acc1;
        vn[256 + f] = vo[256 + f] + acc2;
    }
}

// ---------------------------------------------------------------------------
// norm/dot from fused uv2 [3N x 256].
// ---------------------------------------------------------------------------
__global__ void norm_kernel(const float* __restrict__ uv2,
                            float* __restrict__ vnorm, float* __restrict__ dotb)
{
    int idx = blockIdx.x * blockDim.x + threadIdx.x;
    if (idx >= NN * 128) return;
    int n = idx >> 7, g = idx & 127;
    const float* base = uv2 + (size_t)n * 768;
    float u0 = base[g],       u1 = base[256 + g], u2 = base[512 + g];
    float v0 = base[128 + g], v1 = base[384 + g], v2 = base[640 + g];
    dotb[idx] = u0 * v0 + u1 * v1 + u2 * v2;
    vnorm[idx] = sqrtf(v0 * v0 + v1 * v1 + v2 * v2 + 1e-15f);
}

// ---------------------------------------------------------------------------
// Final per-layer update: H += a1*dot + a2 ; V += a0*u_v (u from uv2).
// ---------------------------------------------------------------------------
template <int LAST>
__global__ void final_update_kernel(const float* __restrict__ a,
                                    const float* __restrict__ dotb,
                                    const float* __restrict__ uv2,
                                    float* __restrict__ H,
                                    float* __restrict__ Vplanar,
                                    float* __restrict__ Vout)
{
    int idx = blockIdx.x * blockDim.x + threadIdx.x;
    if (idx >= NN * 128) return;
    int n = idx >> 7, g = idx & 127;
    float a0 = a[n * 384 + g];
    float a1 = a[n * 384 + 128 + g];
    float a2 = a[n * 384 + 256 + g];
    H[idx] += a1 * dotb[idx] + a2;
    float* vp = Vplanar + (size_t)n * 384;
    const float* ub = uv2 + (size_t)n * 768;
    float v0 = vp[g]       + a0 * ub[g];
    float v1 = vp[128 + g] + a0 * ub[256 + g];
    float v2 = vp[256 + g] + a0 * ub[512 + g];
    if (LAST) {
        float* o = Vout + (size_t)n * 384 + g * 3;
        o[0] = v0; o[1] = v1; o[2] = v2;
    } else {
        vp[g] = v0; vp[128 + g] = v1; vp[256 + g] = v2;
    }
}

// ---------------------------------------------------------------------------
extern "C" void kernel_launch(void* const* d_in, const int* in_sizes, int n_in,
                              void* d_out, int out_size, void* d_ws, size_t ws_size,
                              hipStream_t stream)
{
    const float* xyz    = (const float*)d_in[0];
    const int*   nbr    = (const int*)d_in[1];
    const float* H_in   = (const float*)d_in[3];
    const float* msgW1  = (const float*)d_in[4];
    const float* msgb1  = (const float*)d_in[5];
    const float* msgW2  = (const float*)d_in[6];
    const float* msgb2  = (const float*)d_in[7];
    const float* distW  = (const float*)d_in[8];
    const float* distb  = (const float*)d_in[9];
    const float* updU   = (const float*)d_in[10];
    const float* updV   = (const float*)d_in[11];
    const float* updW1  = (const float*)d_in[12];
    const float* updb1  = (const float*)d_in[13];
    const float* updW2  = (const float*)d_in[14];
    const float* updb2  = (const float*)d_in[15];

    float* out  = (float*)d_out;
    float* H    = out;                 // N*128
    float* Vout = out + NN * 128;      // N*384 interleaved (n,f,3)

    // ---- workspace carve ----
    float* f = (float*)d_ws;
    float* Va   = f; f += NN * 384;    // planar V buffers
    float* Vb   = f; f += NN * 384;
    float* Vba  = f; f += NN * 384;
    float* Vbb  = f; f += NN * 384;
    float* Sbar = f; f += NN * 128;
    float* phi  = f; f += NN * 640;
    float* uv2  = f; f += NN * 768;    // [3N x 256] fused u_v|v_v
    float4* ueP = (float4*)f; f += NE * 4;
    float* rbfP  = f; f += NE * NRBF;
    unsigned short* us = (unsigned short*)f;
    unsigned short* X1h = us; us += NN * 256;
    unsigned short* X1l = us; us += NN * 256;
    unsigned short* W1h = us; us += 3 * 256 * 256;   // transposed [N=256][K=256]
    unsigned short* W1l = us; us += 3 * 256 * 256;
    unsigned short* W2h = us; us += 3 * 256 * 640;   // transposed [N=640][K=256]
    unsigned short* W2l = us; us += 3 * 256 * 640;
    unsigned short* UVh = us; us += 3 * 128 * 256;   // transposed [N=256][K=128]
    unsigned short* UVl = us; us += 3 * 128 * 256;
    unsigned short* uW1h = us; us += 3 * 256 * 128;  // transposed [N=128][K=256]
    unsigned short* uW1l = us; us += 3 * 256 * 128;
    unsigned short* uW2h = us; us += 3 * 128 * 384;  // transposed [N=384][K=128]
    unsigned short* uW2l = us; us += 3 * 128 * 384;
    int* ip = (int*)(((size_t)us + 15) & ~(size_t)15);
    int* counts  = ip; ip += NN;
    int* offsets = ip; ip += NN + 1;
    int* cnt2    = ip; ip += NN;
    int* dstP    = ip; ip += NE;
    // aliases into dead phi region (phi dead after gather each layer)
    float* vnorm = phi;
    float* dotb  = phi + NN * 128;
    float* abuf  = phi + NN * 256;     // N*384

    // ---- init ----
    hipMemsetAsync(counts, 0, NN * sizeof(int), stream);
    hipMemsetAsync(cnt2, 0, NN * sizeof(int), stream);
    hipMemsetAsync(Sbar, 0, (size_t)NN * 128 * sizeof(float), stream);
    hipMemcpyAsync(H, H_in, (size_t)NN * 128 * sizeof(float),
                   hipMemcpyDeviceToDevice, stream);

    // ---- edge CSR + geometry + weight transpose/split ----
    edge_count_kernel<<<(NE + 255) / 256, 256, 0, stream>>>(nbr, counts);
    scan_kernel<<<1, 1024, 0, stream>>>(counts, offsets);
    edge_geom_fill_kernel<<<(NE + 255) / 256, 256, 0, stream>>>(xyz, nbr, offsets, cnt2,
                                                                dstP, ueP, rbfP);
    tsplit_kernel<<<(3 * 256 * 256 + 255) / 256, 256, 0, stream>>>(msgW1, W1h, W1l, 256, 256);
    tsplit_kernel<<<(3 * 256 * 640 + 255) / 256, 256, 0, stream>>>(msgW2, W2h, W2l, 256, 640);
    tsplit_kernel<<<(3 * 256 * 128 + 255) / 256, 256, 0, stream>>>(updW1, uW1h, uW1l, 256, 128);
    tsplit_kernel<<<(3 * 128 * 384 + 255) / 256, 256, 0, stream>>>(updW2, uW2h, uW2l, 128, 384);
    build_uvcat_t_kernel<<<(3 * 128 * 256 + 255) / 256, 256, 0, stream>>>(updU, updV, UVh, UVl);

    for (int l = 0; l < 3; ++l) {
        const float* b1 = msgb1 + (size_t)l * 256;
        const float* b2 = msgb2 + (size_t)l * 640;
        const float* dW = distW + (size_t)l * NRBF * 640;
        const float* db = distb + (size_t)l * 640;
        const float* ub1 = updb1 + (size_t)l * 128;
        const float* ub2 = updb2 + (size_t)l * 384;
        const unsigned short *w1h = W1h + (size_t)l * 256 * 256, *w1l = W1l + (size_t)l * 256 * 256;
        const unsigned short *w2h = W2h + (size_t)l * 256 * 640, *w2l = W2l + (size_t)l * 256 * 640;
        const unsigned short *uvh = UVh + (size_t)l * 128 * 256, *uvl = UVl + (size_t)l * 128 * 256;
        const unsigned short *u1h = uW1h + (size_t)l * 256 * 128, *u1l = uW1l + (size_t)l * 256 * 128;
        const unsigned short *u2h = uW2h + (size_t)l * 128 * 384, *u2l = uW2l + (size_t)l * 128 * 384;

        float *Vold, *Vnew, *Vbold, *Vbnew;
        if (l == 0)      { Vold = Va; Vnew = Vb; Vbold = Vba; Vbnew = Vbb; }
        else if (l == 1) { Vold = Vb; Vnew = Va; Vbold = Vbb; Vbnew = Vba; }
        else             { Vold = Va; Vnew = Vb; Vbold = Vba; Vbnew = Vbb; }

        // X1 = silu([H|Sbar] @ W1 + b1)  (split-bf16 output)
        {
            dim3 g(256 / 64, (NN + 63) / 64);
            gemm5_kernel<1, 1, 0, 1><<<g, 256, 0, stream>>>(
                H, Sbar, nullptr, nullptr, w1h, w1l, b1,
                nullptr, X1h, X1l, NN, 256, 256);
        }
        // phi = X1 @ W2 + b2  (fp32 output)
        {
            dim3 g(640 / 64, (NN + 63) / 64);
            gemm5_kernel<0, 0, 1, 0><<<g, 256, 0, stream>>>(
                nullptr, nullptr, X1h, X1l, w2h, w2l, b2,
                phi, nullptr, nullptr, NN, 256, 640);
        }

        // message gather
        if (l == 0)
            gather_kernel<1><<<NN, 256, 0, stream>>>(offsets, dstP, ueP, rbfP,
                                                     phi, dW, db, Vold, Vbold,
                                                     H, Sbar, Vnew, Vbnew);
        else
            gather_kernel<0><<<NN, 256, 0, stream>>>(offsets, dstP, ueP, rbfP,
                                                     phi, dW, db, Vold, Vbold,
                                                     H, Sbar, Vnew, Vbnew);

        // uv2[3N x 256] = Vplanar[3N x 128] @ [U|V]
        {
            dim3 g(256 / 64, (3 * NN + 63) / 64);
            gemm5_kernel<0, 0, 0, 0><<<g, 256, 0, stream>>>(
                Vnew, nullptr, nullptr, nullptr, uvh, uvl, nullptr,
                uv2, nullptr, nullptr, 3 * NN, 128, 256);
        }
        norm_kernel<<<(NN * 128 + 255) / 256, 256, 0, stream>>>(uv2, vnorm, dotb);

        // X1 = silu([H|vnorm] @ uW1 + ub1)  (split output, 128 wide)
        {
            dim3 g(128 / 64, (NN + 63) / 64);
            gemm5_kernel<1, 1, 0, 1><<<g, 256, 0, stream>>>(
                H, vnorm, nullptr, nullptr, u1h, u1l, ub1,
                nullptr, X1h, X1l, NN, 256, 128);
        }
        // abuf = X1 @ uW2 + ub2
        {
            dim3 g(384 / 64, (NN + 63) / 64);
            gemm5_kernel<0, 0, 1, 0><<<g, 256, 0, stream>>>(
                nullptr, nullptr, X1h, X1l, u2h, u2l, ub2,
                abuf, nullptr, nullptr, NN, 128, 384);
        }

        // H += a1*dot + a2 ; V += a0*u_v
        if (l < 2)
            final_update_kernel<0><<<(NN * 128 + 255) / 256, 256, 0, stream>>>(
                abuf, dotb, uv2, H, Vnew, nullptr);
        else
            final_update_kernel<1><<<(NN * 128 + 255) / 256, 256, 0, stream>>>(
                abuf, dotb, uv2, H, Vnew, Vout);
    }
}